// Round 1
// 25378.444 us; speedup vs baseline: 1.0911x; 1.0911x over previous
//
#include <hip/hip_runtime.h>
#include <hip/hip_cooperative_groups.h>
#include <hip/hip_bf16.h>
#include <cstddef>

namespace cg = cooperative_groups;

typedef unsigned short u16;
typedef __attribute__((ext_vector_type(8))) short s8;   // 8 bf16 = 4 VGPRs
typedef __attribute__((ext_vector_type(4))) float f4;   // MFMA acc

constexpr int kB = 64, kT = 256, kD = 128, kH = 1024, kL = 5, kC = 10, kG = 4096;
constexpr int BH = kB * kH;
constexpr size_t WLA_ELEMS = (size_t)256 * 8 * 16384;   // 67 MB of u16
constexpr size_t WLB_ELEMS = (size_t)256 * 8 * 2560;    // 10.5 MB
constexpr size_t H_ELEMS = (size_t)kL * 2 * BH;

// h activations are stored FRAGMENT-CONTIGUOUS: H2[k>>3][b][k&7] (u16), i.e.
// flat index ((k>>3)*64 + b)*8 + (k&7). A-fragment load for (k-chunk kk8, rows
// mt*16+r) = 16B at ((kk8*64 + mt*16 + r)*8): lanes r give 256B contiguous,
// quad strides 1KB -> 4 transactions/load instead of 16.
//
// THIS REVISION: the lo-weight stream (chunks 4..15 of wlA) no longer round-
// trips through VGPRs with a 2-deep wlq prefetch; it is DMA'd into a 4-slot
// LDS ring via global_load_lds (async, zero VGPR cost), consumed with a
// counted s_waitcnt vmcnt(4) that keeps 2-3 chunk-DMAs in flight across the
// whole p-loop. The 16 VGPRs freed by deleting wlq fund a 1-iter prefetch of
// the activation-LO fragments (al_n), which were previously loaded at-use
// (one cold-miss latency per p-iteration). Parked input-lo shrinks 8->4
// chunks so LDS stays at exactly 152,576 B (same occupancy).

__device__ __forceinline__ float sigf(float x) { return 1.f / (1.f + __expf(-x)); }
__device__ __forceinline__ float tanh_s(float x) {
  float ax = fabsf(x);
  float e = __expf(-2.f * ax);
  float r = (1.f - e) / (1.f + e);
  return copysignf(r, x);
}
__device__ __forceinline__ void split_bf16(float v, short& hi, short& lo) {
  __hip_bfloat16 h = __float2bfloat16(v);
  hi = __builtin_bit_cast(short, h);
  float fh = __bfloat162float(h);
  __hip_bfloat16 l = __float2bfloat16(v - fh);
  lo = __builtin_bit_cast(short, l);
}
__device__ __forceinline__ short hi_bf16(float v) {
  __hip_bfloat16 h = __float2bfloat16(v);
  return __builtin_bit_cast(short, h);
}
__device__ __forceinline__ float bf2f(u16 v) {
  unsigned u = ((unsigned)v) << 16;
  return __builtin_bit_cast(float, u);
}

// async 16B/lane global->LDS DMA. LDS dest is wave-uniform base + lane*16;
// global src is per-lane. Tracked by vmcnt.
__device__ __forceinline__ void dma16(const void* gsrc, void* ldst) {
  __builtin_amdgcn_global_load_lds(
      (const __attribute__((address_space(1))) void*)gsrc,
      (__attribute__((address_space(3))) void*)ldst, 16, 0, 0);
}

// ---- prep: split weights, write LO parts in per-(block,wave) fragment order ----
__global__ void __launch_bounds__(512) split_wl(const float* __restrict__ Wx0,
                                                const float* __restrict__ Wxs,
                                                const float* __restrict__ Whs,
                                                u16* __restrict__ wlA,
                                                u16* __restrict__ wlB) {
  const int g = blockIdx.x, tid = threadIdx.x;
  const int wv = tid >> 6, lane = tid & 63, quad = lane >> 4, r = lane & 15;
  const int lA = (g >> 6) + 1, jb = g & 63, kq = wv & 3, ch = wv >> 2;
  const float* WxA = Wxs + (size_t)(lA - 1) * kH * kG;
  const float* WhA = Whs + (size_t)lA * kH * kG;

  u16* dA = wlA + (size_t)(g * 8 + wv) * 16384;
  for (int p = 0; p < 16; ++p) {
    int kc = 4 * p + kq;
    const float* W = (kc < 32) ? WxA : WhA;
    int krow0 = (kc & 31) * 32 + quad * 8;
    for (int ntl = 0; ntl < 2; ++ntl) {
      int col = (2 * ch + ntl) * kH + jb * 16 + r;
      s8 l8;
      for (int j = 0; j < 8; ++j) {
        float w = W[(size_t)(krow0 + j) * kG + col];
        short hh, ll;
        split_bf16(w, hh, ll);
        l8[j] = ll;
      }
      *(s8*)(dA + (size_t)((p * 2 + ntl) * 64 + lane) * 8) = l8;
    }
  }

  u16* dB = wlB + (size_t)(g * 8 + wv) * 2560;
  int colB = (r >> 2) * kH + g * 4 + (r & 3);
  for (int j2 = 0; j2 < 4; ++j2) {
    int kb = (wv & 3) + 4 * (2 * j2 + (wv >> 2));
    int krow0 = kb * 32 + quad * 8;
    s8 l8;
    for (int j = 0; j < 8; ++j) {
      float w = Whs[(size_t)(krow0 + j) * kG + colB];
      short hh, ll;
      split_bf16(w, hh, ll);
      l8[j] = ll;
    }
    *(s8*)(dB + (size_t)(j2 * 64 + lane) * 8) = l8;
  }
  {
    int krow0 = (wv & 3) * 32 + quad * 8;
    s8 l8;
    for (int j = 0; j < 8; ++j) {
      float w = Wx0[(size_t)(krow0 + j) * kG + colB];
      short hh, ll;
      split_bf16(w, hh, ll);
      l8[j] = ll;
    }
    *(s8*)(dB + (size_t)(4 * 64 + lane) * 8) = l8;
  }
}

// ---- main persistent kernel ----
__global__ void __launch_bounds__(512, 2) lstm_persist(
    const float* __restrict__ x, const float* __restrict__ Wx0,
    const float* __restrict__ Wxs, const float* __restrict__ Whs,
    const float* __restrict__ bs, const float* __restrict__ W_head,
    const float* __restrict__ b_head, float* __restrict__ out,
    u16* __restrict__ hhi, u16* __restrict__ hlo,
    const u16* __restrict__ wlA, const u16* __restrict__ wlB) {
  cg::grid_group grid = cg::this_grid();
  __shared__ s8 wpark[8][4][2][64];  // 64 KB: parked Wx-lo chunks p=0..3
  __shared__ s8 wring[8][4][2][64];  // 64 KB: 4-slot DMA ring, chunks 4..15
  __shared__ float zA[64 * 66];
  __shared__ float zB[64 * 18];

  const int tid = threadIdx.x;
  const int wv = tid >> 6, lane = tid & 63, quad = lane >> 4, r = lane & 15;
  const int ch = wv >> 2, kq = wv & 3;
  const int g = blockIdx.x;
  const int lA = (g >> 6) + 1;
  const int jb = g & 63;
  const int ub = g * 4;

  const float* __restrict__ WxA = Wxs + (size_t)(lA - 1) * kH * kG;
  const float* __restrict__ WhA = Whs + (size_t)lA * kH * kG;

  // ---- one-time: HI weight fragments into registers (AGPR-backed) ----
  s8 wA[16][2];  // 128 regs
#pragma unroll
  for (int p = 0; p < 16; ++p) {
    int kc = 4 * p + kq;
    const float* W = (kc < 32) ? WxA : WhA;
    int krow0 = (kc & 31) * 32 + quad * 8;
#pragma unroll
    for (int ntl = 0; ntl < 2; ++ntl) {
      int col = (2 * ch + ntl) * kH + jb * 16 + r;
      s8 h8;
#pragma unroll
      for (int j = 0; j < 8; ++j) h8[j] = hi_bf16(W[(size_t)(krow0 + j) * kG + col]);
      wA[p][ntl] = h8;
    }
  }
  s8 wBh[4], wBx;
  {
    int colB = (r >> 2) * kH + ub + (r & 3);
#pragma unroll
    for (int j2 = 0; j2 < 4; ++j2) {
      int kb = (wv & 3) + 4 * (2 * j2 + (wv >> 2));
      int krow0 = kb * 32 + quad * 8;
      s8 h8;
#pragma unroll
      for (int j = 0; j < 8; ++j) h8[j] = hi_bf16(Whs[(size_t)(krow0 + j) * kG + colB]);
      wBh[j2] = h8;
    }
    int krow0 = (wv & 3) * 32 + quad * 8;
    s8 h8;
#pragma unroll
    for (int j = 0; j < 8; ++j) h8[j] = hi_bf16(Wx0[(size_t)(krow0 + j) * kG + colB]);
    wBx = h8;
  }

  const u16* wlAs = wlA + (size_t)(g * 8 + wv) * 16384;
  const u16* wlBs = wlB + (size_t)(g * 8 + wv) * 2560;

  // ---- one-time: parked Wx-lo fragments (p=0..3) into LDS ----
#pragma unroll
  for (int p = 0; p < 4; ++p)
#pragma unroll
    for (int ntl = 0; ntl < 2; ++ntl)
      wpark[wv][p][ntl][lane] =
          *(const s8*)(wlAs + (size_t)((p * 2 + ntl) * 64 + lane) * 8);

  float bA[4], bB[4];
  {
    int u = tid & 15;
#pragma unroll
    for (int g4 = 0; g4 < 4; ++g4) bA[g4] = bs[(size_t)lA * kG + g4 * kH + jb * 16 + u];
    int u2 = tid & 3;
#pragma unroll
    for (int g4 = 0; g4 < 4; ++g4) bB[g4] = bs[(size_t)g4 * kH + ub + u2];
  }
  float cA0 = 0.f, cA1 = 0.f, cB0 = 0.f;
  const s8 zf = {0, 0, 0, 0, 0, 0, 0, 0};
  const f4 zero4 = {0.f, 0.f, 0.f, 0.f};
  const int fragbase = kq * 4 + quad;  // kk8 offset within a 16-group (128 k)

  __syncthreads();

  // ---- wavefront loop ----
  for (int s = 0; s < kT + kL - 1; ++s) {
    const int tA = s - lA;
    const int tB = s;

    for (int i = tid; i < 64 * 66; i += 512) zA[i] = 0.f;
    for (int i = tid; i < 64 * 18; i += 512) zB[i] = 0.f;
    __syncthreads();

    // ---- task A: 64 cols of layer lA; p=0..3 parked-LDS, 4..15 via DMA ring ----
    if (tA >= 0 && tA < kT) {
      const u16* IH = hhi + (size_t)((lA - 1) * 2 + (tA & 1)) * BH;
      const u16* IL = hlo + (size_t)((lA - 1) * 2 + (tA & 1)) * BH;
      const u16* RH = hhi + (size_t)(lA * 2 + ((tA - 1) & 1)) * BH;
      const u16* RL = hlo + (size_t)(lA * 2 + ((tA - 1) & 1)) * BH;
      const bool zz = (tA == 0);
      f4 accA[2][4];
#pragma unroll
      for (int a = 0; a < 2; ++a)
#pragma unroll
        for (int b = 0; b < 4; ++b) accA[a][b] = zero4;

      // prologue: start ring DMAs for chunks 4,5 and prefetch h for p=0.
#pragma unroll
      for (int c = 4; c <= 5; ++c)
#pragma unroll
        for (int ntl = 0; ntl < 2; ++ntl)
          dma16(wlAs + (size_t)((c * 2 + ntl) * 64 + lane) * 8,
                &wring[wv][c & 3][ntl][0]);
      s8 ah_n[4], al_n[4];
#pragma unroll
      for (int mt = 0; mt < 4; ++mt) {
        ah_n[mt] = *(const s8*)(IH + (size_t)(fragbase * 64 + mt * 16 + r) * 8);
        al_n[mt] = *(const s8*)(IL + (size_t)(fragbase * 64 + mt * 16 + r) * 8);
      }

#pragma unroll
      for (int p = 0; p < 16; ++p) {
        const bool curR = (p >= 8);
        // pin iteration boundary: nothing moves across (keeps the vmcnt
        // counting argument valid and orders ring read-vs-refill).
        __builtin_amdgcn_sched_barrier(0);
        if (p >= 4) {
          // chunk p's 2 DMAs were issued >=3 iters ago and have >=4 younger
          // vmem ops (chunks p+1,p+2 DMAs at minimum); vmcnt retires in
          // issue order, so <=4 outstanding => chunk p landed in LDS.
          // Also completes the h prefetch issued last iteration.
          asm volatile("s_waitcnt vmcnt(4)" ::: "memory");
          __builtin_amdgcn_sched_barrier(0);
        }
        // wl for current p
        s8 wl0, wl1;
        if (p < 4) {
          wl0 = wpark[wv][p][0][lane];
          wl1 = wpark[wv][p][1][lane];
        } else {
          wl0 = wring[wv][p & 3][0][lane];
          wl1 = wring[wv][p & 3][1][lane];
        }
        // current h frags (prefetched last iter), zero-masked at t==0
        s8 ah_c[4], al_c[4];
#pragma unroll
        for (int mt = 0; mt < 4; ++mt) {
          ah_c[mt] = (curR && zz) ? zf : ah_n[mt];
          al_c[mt] = (curR && zz) ? zf : al_n[mt];
        }
        // prefetch next h (hi AND lo)
        if (p < 15) {
          const int pn = p + 1;
          const u16* SH = (pn >= 8) ? RH : IH;
          const u16* SL = (pn >= 8) ? RL : IL;
          const int kb8 = ((pn & 7) * 16 + fragbase) * 64;
#pragma unroll
          for (int mt = 0; mt < 4; ++mt) {
            ah_n[mt] = *(const s8*)(SH + (size_t)(kb8 + mt * 16 + r) * 8);
            al_n[mt] = *(const s8*)(SL + (size_t)(kb8 + mt * 16 + r) * 8);
          }
        }
        // ring refill, distance 3: chunk p+3 -> slot (p+3)&3 == (p-1)&3,
        // whose previous tenant (chunk p-1) was register-captured last iter.
        if (p >= 3 && p <= 12) {
          const int c = p + 3;
#pragma unroll
          for (int ntl = 0; ntl < 2; ++ntl)
            dma16(wlAs + (size_t)((c * 2 + ntl) * 64 + lane) * 8,
                  &wring[wv][c & 3][ntl][0]);
        }
#pragma unroll
        for (int mt = 0; mt < 4; ++mt) {
          f4 a0 = accA[0][mt], a1 = accA[1][mt];
          a0 = __builtin_amdgcn_mfma_f32_16x16x32_bf16(ah_c[mt], wA[p][0], a0, 0, 0, 0);
          a0 = __builtin_amdgcn_mfma_f32_16x16x32_bf16(al_c[mt], wA[p][0], a0, 0, 0, 0);
          a0 = __builtin_amdgcn_mfma_f32_16x16x32_bf16(ah_c[mt], wl0, a0, 0, 0, 0);
          a1 = __builtin_amdgcn_mfma_f32_16x16x32_bf16(ah_c[mt], wA[p][1], a1, 0, 0, 0);
          a1 = __builtin_amdgcn_mfma_f32_16x16x32_bf16(al_c[mt], wA[p][1], a1, 0, 0, 0);
          a1 = __builtin_amdgcn_mfma_f32_16x16x32_bf16(ah_c[mt], wl1, a1, 0, 0, 0);
          accA[0][mt] = a0;
          accA[1][mt] = a1;
        }
      }
#pragma unroll
      for (int ntl = 0; ntl < 2; ++ntl)
#pragma unroll
        for (int mt = 0; mt < 4; ++mt)
#pragma unroll
          for (int v = 0; v < 4; ++v)
            atomicAdd(&zA[(mt * 16 + quad * 4 + v) * 66 + (2 * ch + ntl) * 16 + r],
                      accA[ntl][mt][v]);
    }

    // ---- task B: 4 units of layer 0 ----
    if (tB < kT) {
      const u16* H0H = hhi + (size_t)((tB - 1) & 1) * BH;
      const u16* H0L = hlo + (size_t)((tB - 1) & 1) * BH;
      const bool z0 = (tB == 0);
      f4 accB[4];
#pragma unroll
      for (int b = 0; b < 4; ++b) accB[b] = zero4;

      s8 wlb_n = *(const s8*)(wlBs + (size_t)(0 * 64 + lane) * 8);
      s8 ahb_n[4];
      {
        const int kb0 = (wv & 3) + 4 * (wv >> 2);
        const int kb8 = (kb0 * 4 + quad) * 64;
#pragma unroll
        for (int mt = 0; mt < 4; ++mt)
          ahb_n[mt] = *(const s8*)(H0H + (size_t)(kb8 + mt * 16 + r) * 8);
      }
#pragma unroll
      for (int j2 = 0; j2 < 4; ++j2) {
        const int kb = (wv & 3) + 4 * (2 * j2 + (wv >> 2));
        const int kb8c = (kb * 4 + quad) * 64;
        s8 wlv = wlb_n;
        s8 ahb_c[4];
#pragma unroll
        for (int mt = 0; mt < 4; ++mt) ahb_c[mt] = z0 ? zf : ahb_n[mt];
        if (j2 < 3) {
          wlb_n = *(const s8*)(wlBs + (size_t)((j2 + 1) * 64 + lane) * 8);
          const int kbn = (wv & 3) + 4 * (2 * (j2 + 1) + (wv >> 2));
          const int kb8n = (kbn * 4 + quad) * 64;
#pragma unroll
          for (int mt = 0; mt < 4; ++mt)
            ahb_n[mt] = *(const s8*)(H0H + (size_t)(kb8n + mt * 16 + r) * 8);
        }
        s8 alb[4];
#pragma unroll
        for (int mt = 0; mt < 4; ++mt) {
          s8 v = *(const s8*)(H0L + (size_t)(kb8c + mt * 16 + r) * 8);
          alb[mt] = z0 ? zf : v;
        }
#pragma unroll
        for (int mt = 0; mt < 4; ++mt) {
          f4 a = accB[mt];
          a = __builtin_amdgcn_mfma_f32_16x16x32_bf16(ahb_c[mt], wBh[j2], a, 0, 0, 0);
          a = __builtin_amdgcn_mfma_f32_16x16x32_bf16(alb[mt], wBh[j2], a, 0, 0, 0);
          a = __builtin_amdgcn_mfma_f32_16x16x32_bf16(ahb_c[mt], wlv, a, 0, 0, 0);
          accB[mt] = a;
        }
      }
      if (wv >= 4) {
        const int c = wv - 4;
        s8 wlx = *(const s8*)(wlBs + (size_t)(4 * 64 + lane) * 8);
#pragma unroll
        for (int mt = 0; mt < 4; ++mt) {
          const float* sx =
              x + (size_t)(mt * 16 + r) * kT * kD + (size_t)tB * kD + c * 32 + quad * 8;
          float4 v0 = *(const float4*)sx;
          float4 v1 = *(const float4*)(sx + 4);
          float vv[8] = {v0.x, v0.y, v0.z, v0.w, v1.x, v1.y, v1.z, v1.w};
          s8 xh, xl;
#pragma unroll
          for (int e = 0; e < 8; ++e) {
            short hh, ll;
            split_bf16(vv[e], hh, ll);
            xh[e] = hh;
            xl[e] = ll;
          }
          f4 a = accB[mt];
          a = __builtin_amdgcn_mfma_f32_16x16x32_bf16(xh, wBx, a, 0, 0, 0);
          a = __builtin_amdgcn_mfma_f32_16x16x32_bf16(xl, wBx, a, 0, 0, 0);
          a = __builtin_amdgcn_mfma_f32_16x16x32_bf16(xh, wlx, a, 0, 0, 0);
          accB[mt] = a;
        }
      }
#pragma unroll
      for (int mt = 0; mt < 4; ++mt)
#pragma unroll
        for (int v = 0; v < 4; ++v)
          atomicAdd(&zB[(mt * 16 + quad * 4 + v) * 18 + r], accB[mt][v]);
    }

    __syncthreads();

    // ---- gates + h store (fragment-contiguous H2 layout) ----
    if (tA >= 0 && tA < kT) {
      const int par = tA & 1;
      u16* HH = hhi + (size_t)(lA * 2 + par) * BH;
      u16* HL = hlo + (size_t)(lA * 2 + par) * BH;
#pragma unroll
      for (int rp = 0; rp < 2; ++rp) {
        int p2 = tid + 512 * rp;
        int b = p2 >> 4, u = p2 & 15;
        float zi = zA[b * 66 + u] + bA[0];
        float zfg = zA[b * 66 + 16 + u] + bA[1];
        float zg = zA[b * 66 + 32 + u] + bA[2];
        float zo = zA[b * 66 + 48 + u] + bA[3];
        float cp = (tA == 0) ? 0.f : (rp ? cA1 : cA0);
        float cn = sigf(zfg) * cp + sigf(zi) * tanh_s(zg);
        float hn = sigf(zo) * tanh_s(cn);
        if (rp) cA1 = cn; else cA0 = cn;
        short hh, ll;
        split_bf16(hn, hh, ll);
        size_t off = ((size_t)(jb * 2 + (u >> 3)) * 64 + b) * 8 + (u & 7);
        HH[off] = (u16)hh;
        HL[off] = (u16)ll;
      }
    }
    if (tB < kT && tid < 256) {
      const int par = tB & 1;
      u16* HH = hhi + (size_t)par * BH;
      u16* HL = hlo + (size_t)par * BH;
      int b = tid >> 2, u2 = tid & 3;
      float zi = zB[b * 18 + u2] + bB[0];
      float zfg = zB[b * 18 + 4 + u2] + bB[1];
      float zg = zB[b * 18 + 8 + u2] + bB[2];
      float zo = zB[b * 18 + 12 + u2] + bB[3];
      float cp = (tB == 0) ? 0.f : cB0;
      float cn = sigf(zfg) * cp + sigf(zi) * tanh_s(zg);
      float hn = sigf(zo) * tanh_s(cn);
      cB0 = cn;
      short hh, ll;
      split_bf16(hn, hh, ll);
      int uglob = ub + u2;
      size_t off = ((size_t)(uglob >> 3) * 64 + b) * 8 + (uglob & 7);
      HH[off] = (u16)hh;
      HL[off] = (u16)ll;
    }

    grid.sync();
  }

  // ---- head ----
  if (g < 80) {
    int p = g * 8 + wv;
    int b = p / 10, cc = p - b * 10;
    const u16* HH = hhi + (size_t)(4 * 2 + 1) * BH;
    const u16* HL = hlo + (size_t)(4 * 2 + 1) * BH;
    float sum = 0.f;
    for (int j = lane; j < kH; j += 64) {
      size_t off = ((size_t)(j >> 3) * 64 + b) * 8 + (j & 7);
      sum += (bf2f(HH[off]) + bf2f(HL[off])) * W_head[(size_t)j * kC + cc];
    }
#pragma unroll
    for (int off = 32; off > 0; off >>= 1) sum += __shfl_down(sum, off, 64);
    if (lane == 0) out[p] = sum + b_head[cc];
  }
}

// Fallback weight-lo buffer, allocated at library load (NOT inside kernel_launch).
static u16* g_wl = nullptr;
__attribute__((constructor)) static void alloc_wl() {
  hipMalloc((void**)&g_wl, (WLA_ELEMS + WLB_ELEMS) * sizeof(u16));
}

extern "C" void kernel_launch(void* const* d_in, const int* in_sizes, int n_in,
                              void* d_out, int out_size, void* d_ws, size_t ws_size,
                              hipStream_t stream) {
  const float* x = (const float*)d_in[0];
  const float* Wx0 = (const float*)d_in[1];
  const float* Wxs = (const float*)d_in[2];
  const float* Whs = (const float*)d_in[3];
  const float* bs = (const float*)d_in[4];
  const float* W_head = (const float*)d_in[5];
  const float* b_head = (const float*)d_in[6];
  float* out = (float*)d_out;

  u16* hhi = (u16*)d_ws;
  u16* hlo = hhi + H_ELEMS;
  u16* ws_wl = hlo + H_ELEMS;
  size_t need = (2 * H_ELEMS + WLA_ELEMS + WLB_ELEMS) * sizeof(u16);
  u16 *wlA, *wlB;
  if (ws_size >= need) {
    wlA = ws_wl;
    wlB = wlA + WLA_ELEMS;
  } else {
    wlA = g_wl;
    wlB = g_wl + WLA_ELEMS;
  }

  split_wl<<<256, 512, 0, stream>>>(Wx0, Wxs, Whs, wlA, wlB);

  void* args[] = {&x, &Wx0, &Wxs, &Whs, &bs, &W_head, &b_head,
                  &out, &hhi, &hlo, &wlA, &wlB};
  hipLaunchCooperativeKernel((void*)lstm_persist, dim3(256), dim3(512), args, 0,
                             stream);
}

// Round 2
// 22639.282 us; speedup vs baseline: 1.2231x; 1.1210x over previous
//
#include <hip/hip_runtime.h>
#include <hip/hip_cooperative_groups.h>
#include <hip/hip_bf16.h>
#include <cstddef>

typedef unsigned short u16;
typedef unsigned long long u64t;
typedef __attribute__((ext_vector_type(8))) short s8;   // 8 bf16 = 4 VGPRs
typedef __attribute__((ext_vector_type(4))) float f4;   // MFMA acc
typedef __attribute__((ext_vector_type(2))) unsigned long long u64x2;

constexpr int kB = 64, kT = 256, kD = 128, kH = 1024, kL = 5, kC = 10, kG = 4096;
constexpr int BH = kB * kH;
constexpr size_t WLA_ELEMS = (size_t)256 * 8 * 16384;   // 67 MB of u16
constexpr size_t WLB_ELEMS = (size_t)256 * 8 * 2560;    // 10.5 MB
constexpr size_t H_ELEMS = (size_t)kL * 2 * BH;
constexpr int NBLK = 256;

// h activations are stored FRAGMENT-CONTIGUOUS: H2[k>>3][b][k&7] (u16), i.e.
// flat index ((k>>3)*64 + b)*8 + (k&7).
//
// THIS REVISION: cg::grid.sync() is GONE. Its device-scope acquire/release
// (L2 writeback+invalidate on all 8 XCDs, fenced spin) was the per-step wall:
// the compute/memory ledger accounts for <=20 us of the measured 96 us/step.
// Replacement:
//   * all cross-block h traffic uses agent-scope relaxed atomics (sc0 sc1,
//     L2-bypassing, coherent at L3) -> no cache maintenance needed, and L2
//     retains read-only data (x, parked wl) across steps;
//   * per-step barrier = per-wave vmcnt drain -> __syncthreads -> thread0
//     release fetch_add on bar[s] -> relaxed spin to 256 -> __syncthreads.
// Cooperative launch is kept solely for co-residency.

__device__ __forceinline__ float sigf(float x) { return 1.f / (1.f + __expf(-x)); }
__device__ __forceinline__ float tanh_s(float x) {
  float ax = fabsf(x);
  float e = __expf(-2.f * ax);
  float r = (1.f - e) / (1.f + e);
  return copysignf(r, x);
}
__device__ __forceinline__ void split_bf16(float v, short& hi, short& lo) {
  __hip_bfloat16 h = __float2bfloat16(v);
  hi = __builtin_bit_cast(short, h);
  float fh = __bfloat162float(h);
  __hip_bfloat16 l = __float2bfloat16(v - fh);
  lo = __builtin_bit_cast(short, l);
}
__device__ __forceinline__ short hi_bf16(float v) {
  __hip_bfloat16 h = __float2bfloat16(v);
  return __builtin_bit_cast(short, h);
}
__device__ __forceinline__ float bf2f(u16 v) {
  unsigned u = ((unsigned)v) << 16;
  return __builtin_bit_cast(float, u);
}

// ---- agent-coherent (cross-XCD) h accessors: bypass L2, meet at L3 ----
__device__ __forceinline__ s8 ldh16(const u16* p) {
  u64x2 v;
  v.x = __hip_atomic_load((const u64t*)p, __ATOMIC_RELAXED, __HIP_MEMORY_SCOPE_AGENT);
  v.y = __hip_atomic_load((const u64t*)p + 1, __ATOMIC_RELAXED, __HIP_MEMORY_SCOPE_AGENT);
  return __builtin_bit_cast(s8, v);
}
__device__ __forceinline__ u16 ldh(const u16* p) {
  return __hip_atomic_load(p, __ATOMIC_RELAXED, __HIP_MEMORY_SCOPE_AGENT);
}
__device__ __forceinline__ void sth(u16* p, u16 v) {
  __hip_atomic_store(p, v, __ATOMIC_RELAXED, __HIP_MEMORY_SCOPE_AGENT);
}

// async 16B/lane global->LDS DMA. LDS dest is wave-uniform base + lane*16;
// global src is per-lane. Tracked by vmcnt.
__device__ __forceinline__ void dma16(const void* gsrc, void* ldst) {
  __builtin_amdgcn_global_load_lds(
      (const __attribute__((address_space(1))) void*)gsrc,
      (__attribute__((address_space(3))) void*)ldst, 16, 0, 0);
}

// ---- prep: split weights, write LO parts in per-(block,wave) fragment order ----
__global__ void __launch_bounds__(512) split_wl(const float* __restrict__ Wx0,
                                                const float* __restrict__ Wxs,
                                                const float* __restrict__ Whs,
                                                u16* __restrict__ wlA,
                                                u16* __restrict__ wlB,
                                                unsigned* __restrict__ bar) {
  const int g = blockIdx.x, tid = threadIdx.x;
  const int wv = tid >> 6, lane = tid & 63, quad = lane >> 4, r = lane & 15;
  const int lA = (g >> 6) + 1, jb = g & 63, kq = wv & 3, ch = wv >> 2;
  const float* WxA = Wxs + (size_t)(lA - 1) * kH * kG;
  const float* WhA = Whs + (size_t)lA * kH * kG;

  if (g == 0 && tid < 512) bar[tid] = 0;  // re-zero barrier counters each launch

  u16* dA = wlA + (size_t)(g * 8 + wv) * 16384;
  for (int p = 0; p < 16; ++p) {
    int kc = 4 * p + kq;
    const float* W = (kc < 32) ? WxA : WhA;
    int krow0 = (kc & 31) * 32 + quad * 8;
    for (int ntl = 0; ntl < 2; ++ntl) {
      int col = (2 * ch + ntl) * kH + jb * 16 + r;
      s8 l8;
      for (int j = 0; j < 8; ++j) {
        float w = W[(size_t)(krow0 + j) * kG + col];
        short hh, ll;
        split_bf16(w, hh, ll);
        l8[j] = ll;
      }
      *(s8*)(dA + (size_t)((p * 2 + ntl) * 64 + lane) * 8) = l8;
    }
  }

  u16* dB = wlB + (size_t)(g * 8 + wv) * 2560;
  int colB = (r >> 2) * kH + g * 4 + (r & 3);
  for (int j2 = 0; j2 < 4; ++j2) {
    int kb = (wv & 3) + 4 * (2 * j2 + (wv >> 2));
    int krow0 = kb * 32 + quad * 8;
    s8 l8;
    for (int j = 0; j < 8; ++j) {
      float w = Whs[(size_t)(krow0 + j) * kG + colB];
      short hh, ll;
      split_bf16(w, hh, ll);
      l8[j] = ll;
    }
    *(s8*)(dB + (size_t)(j2 * 64 + lane) * 8) = l8;
  }
  {
    int krow0 = (wv & 3) * 32 + quad * 8;
    s8 l8;
    for (int j = 0; j < 8; ++j) {
      float w = Wx0[(size_t)(krow0 + j) * kG + colB];
      short hh, ll;
      split_bf16(w, hh, ll);
      l8[j] = ll;
    }
    *(s8*)(dB + (size_t)(4 * 64 + lane) * 8) = l8;
  }
}

// ---- main persistent kernel ----
__global__ void __launch_bounds__(512, 2) lstm_persist(
    const float* __restrict__ x, const float* __restrict__ Wx0,
    const float* __restrict__ Wxs, const float* __restrict__ Whs,
    const float* __restrict__ bs, const float* __restrict__ W_head,
    const float* __restrict__ b_head, float* __restrict__ out,
    u16* __restrict__ hhi, u16* __restrict__ hlo,
    const u16* __restrict__ wlA, const u16* __restrict__ wlB,
    unsigned* __restrict__ bar) {
  __shared__ s8 wpark[8][4][2][64];  // 64 KB: parked Wx-lo chunks p=0..3
  __shared__ s8 wring[8][4][2][64];  // 64 KB: 4-slot DMA ring, chunks 4..15
  __shared__ float zA[64 * 66];
  __shared__ float zB[64 * 18];

  const int tid = threadIdx.x;
  const int wv = tid >> 6, lane = tid & 63, quad = lane >> 4, r = lane & 15;
  const int ch = wv >> 2, kq = wv & 3;
  const int g = blockIdx.x;
  const int lA = (g >> 6) + 1;
  const int jb = g & 63;
  const int ub = g * 4;

  const float* __restrict__ WxA = Wxs + (size_t)(lA - 1) * kH * kG;
  const float* __restrict__ WhA = Whs + (size_t)lA * kH * kG;

  // ---- one-time: HI weight fragments into registers (AGPR-backed) ----
  s8 wA[16][2];  // 128 regs
#pragma unroll
  for (int p = 0; p < 16; ++p) {
    int kc = 4 * p + kq;
    const float* W = (kc < 32) ? WxA : WhA;
    int krow0 = (kc & 31) * 32 + quad * 8;
#pragma unroll
    for (int ntl = 0; ntl < 2; ++ntl) {
      int col = (2 * ch + ntl) * kH + jb * 16 + r;
      s8 h8;
#pragma unroll
      for (int j = 0; j < 8; ++j) h8[j] = hi_bf16(W[(size_t)(krow0 + j) * kG + col]);
      wA[p][ntl] = h8;
    }
  }
  s8 wBh[4], wBx;
  {
    int colB = (r >> 2) * kH + ub + (r & 3);
#pragma unroll
    for (int j2 = 0; j2 < 4; ++j2) {
      int kb = (wv & 3) + 4 * (2 * j2 + (wv >> 2));
      int krow0 = kb * 32 + quad * 8;
      s8 h8;
#pragma unroll
      for (int j = 0; j < 8; ++j) h8[j] = hi_bf16(Whs[(size_t)(krow0 + j) * kG + colB]);
      wBh[j2] = h8;
    }
    int krow0 = (wv & 3) * 32 + quad * 8;
    s8 h8;
#pragma unroll
    for (int j = 0; j < 8; ++j) h8[j] = hi_bf16(Wx0[(size_t)(krow0 + j) * kG + colB]);
    wBx = h8;
  }

  const u16* wlAs = wlA + (size_t)(g * 8 + wv) * 16384;
  const u16* wlBs = wlB + (size_t)(g * 8 + wv) * 2560;

  // ---- one-time: parked Wx-lo fragments (p=0..3) into LDS ----
#pragma unroll
  for (int p = 0; p < 4; ++p)
#pragma unroll
    for (int ntl = 0; ntl < 2; ++ntl)
      wpark[wv][p][ntl][lane] =
          *(const s8*)(wlAs + (size_t)((p * 2 + ntl) * 64 + lane) * 8);

  float bA[4], bB[4];
  {
    int u = tid & 15;
#pragma unroll
    for (int g4 = 0; g4 < 4; ++g4) bA[g4] = bs[(size_t)lA * kG + g4 * kH + jb * 16 + u];
    int u2 = tid & 3;
#pragma unroll
    for (int g4 = 0; g4 < 4; ++g4) bB[g4] = bs[(size_t)g4 * kH + ub + u2];
  }
  float cA0 = 0.f, cA1 = 0.f, cB0 = 0.f;
  const s8 zf = {0, 0, 0, 0, 0, 0, 0, 0};
  const f4 zero4 = {0.f, 0.f, 0.f, 0.f};
  const int fragbase = kq * 4 + quad;  // kk8 offset within a 16-group (128 k)

  __syncthreads();

  // ---- wavefront loop ----
  for (int s = 0; s < kT + kL - 1; ++s) {
    const int tA = s - lA;
    const int tB = s;

    for (int i = tid; i < 64 * 66; i += 512) zA[i] = 0.f;
    for (int i = tid; i < 64 * 18; i += 512) zB[i] = 0.f;
    __syncthreads();

    // ---- task A: 64 cols of layer lA; p=0..3 parked-LDS, 4..15 via DMA ring ----
    if (tA >= 0 && tA < kT) {
      const u16* IH = hhi + (size_t)((lA - 1) * 2 + (tA & 1)) * BH;
      const u16* IL = hlo + (size_t)((lA - 1) * 2 + (tA & 1)) * BH;
      const u16* RH = hhi + (size_t)(lA * 2 + ((tA - 1) & 1)) * BH;
      const u16* RL = hlo + (size_t)(lA * 2 + ((tA - 1) & 1)) * BH;
      const bool zz = (tA == 0);
      f4 accA[2][4];
#pragma unroll
      for (int a = 0; a < 2; ++a)
#pragma unroll
        for (int b = 0; b < 4; ++b) accA[a][b] = zero4;

      // prologue: start ring DMAs for chunks 4,5 and prefetch h for p=0.
#pragma unroll
      for (int c = 4; c <= 5; ++c)
#pragma unroll
        for (int ntl = 0; ntl < 2; ++ntl)
          dma16(wlAs + (size_t)((c * 2 + ntl) * 64 + lane) * 8,
                &wring[wv][c & 3][ntl][0]);
      s8 ah_n[4], al_n[4];
#pragma unroll
      for (int mt = 0; mt < 4; ++mt) {
        ah_n[mt] = ldh16(IH + (size_t)(fragbase * 64 + mt * 16 + r) * 8);
        al_n[mt] = ldh16(IL + (size_t)(fragbase * 64 + mt * 16 + r) * 8);
      }

#pragma unroll
      for (int p = 0; p < 16; ++p) {
        const bool curR = (p >= 8);
        // pin iteration boundary: nothing moves across (keeps the vmcnt
        // counting argument valid and orders ring read-vs-refill).
        __builtin_amdgcn_sched_barrier(0);
        if (p >= 4) {
          // chunk p's 2 DMAs were issued >=3 iters ago and have >=4 younger
          // vmem ops; vmcnt retires in issue order, so <=4 outstanding =>
          // chunk p landed in LDS. h-register deps are compiler-tracked.
          asm volatile("s_waitcnt vmcnt(4)" ::: "memory");
          __builtin_amdgcn_sched_barrier(0);
        }
        // wl for current p
        s8 wl0, wl1;
        if (p < 4) {
          wl0 = wpark[wv][p][0][lane];
          wl1 = wpark[wv][p][1][lane];
        } else {
          wl0 = wring[wv][p & 3][0][lane];
          wl1 = wring[wv][p & 3][1][lane];
        }
        // current h frags (prefetched last iter), zero-masked at t==0
        s8 ah_c[4], al_c[4];
#pragma unroll
        for (int mt = 0; mt < 4; ++mt) {
          ah_c[mt] = (curR && zz) ? zf : ah_n[mt];
          al_c[mt] = (curR && zz) ? zf : al_n[mt];
        }
        // prefetch next h (hi AND lo)
        if (p < 15) {
          const int pn = p + 1;
          const u16* SH = (pn >= 8) ? RH : IH;
          const u16* SL = (pn >= 8) ? RL : IL;
          const int kb8 = ((pn & 7) * 16 + fragbase) * 64;
#pragma unroll
          for (int mt = 0; mt < 4; ++mt) {
            ah_n[mt] = ldh16(SH + (size_t)(kb8 + mt * 16 + r) * 8);
            al_n[mt] = ldh16(SL + (size_t)(kb8 + mt * 16 + r) * 8);
          }
        }
        // ring refill, distance 3: chunk p+3 -> slot (p+3)&3 == (p-1)&3,
        // whose previous tenant (chunk p-1) was register-captured last iter.
        if (p >= 3 && p <= 12) {
          const int c = p + 3;
#pragma unroll
          for (int ntl = 0; ntl < 2; ++ntl)
            dma16(wlAs + (size_t)((c * 2 + ntl) * 64 + lane) * 8,
                  &wring[wv][c & 3][ntl][0]);
        }
#pragma unroll
        for (int mt = 0; mt < 4; ++mt) {
          f4 a0 = accA[0][mt], a1 = accA[1][mt];
          a0 = __builtin_amdgcn_mfma_f32_16x16x32_bf16(ah_c[mt], wA[p][0], a0, 0, 0, 0);
          a0 = __builtin_amdgcn_mfma_f32_16x16x32_bf16(al_c[mt], wA[p][0], a0, 0, 0, 0);
          a0 = __builtin_amdgcn_mfma_f32_16x16x32_bf16(ah_c[mt], wl0, a0, 0, 0, 0);
          a1 = __builtin_amdgcn_mfma_f32_16x16x32_bf16(ah_c[mt], wA[p][1], a1, 0, 0, 0);
          a1 = __builtin_amdgcn_mfma_f32_16x16x32_bf16(al_c[mt], wA[p][1], a1, 0, 0, 0);
          a1 = __builtin_amdgcn_mfma_f32_16x16x32_bf16(ah_c[mt], wl1, a1, 0, 0, 0);
          accA[0][mt] = a0;
          accA[1][mt] = a1;
        }
      }
#pragma unroll
      for (int ntl = 0; ntl < 2; ++ntl)
#pragma unroll
        for (int mt = 0; mt < 4; ++mt)
#pragma unroll
          for (int v = 0; v < 4; ++v)
            atomicAdd(&zA[(mt * 16 + quad * 4 + v) * 66 + (2 * ch + ntl) * 16 + r],
                      accA[ntl][mt][v]);
    }

    // ---- task B: 4 units of layer 0 ----
    if (tB < kT) {
      const u16* H0H = hhi + (size_t)((tB - 1) & 1) * BH;
      const u16* H0L = hlo + (size_t)((tB - 1) & 1) * BH;
      const bool z0 = (tB == 0);
      f4 accB[4];
#pragma unroll
      for (int b = 0; b < 4; ++b) accB[b] = zero4;

      s8 wlb_n = *(const s8*)(wlBs + (size_t)(0 * 64 + lane) * 8);
      s8 ahb_n[4];
      {
        const int kb0 = (wv & 3) + 4 * (wv >> 2);
        const int kb8 = (kb0 * 4 + quad) * 64;
#pragma unroll
        for (int mt = 0; mt < 4; ++mt)
          ahb_n[mt] = ldh16(H0H + (size_t)(kb8 + mt * 16 + r) * 8);
      }
#pragma unroll
      for (int j2 = 0; j2 < 4; ++j2) {
        const int kb = (wv & 3) + 4 * (2 * j2 + (wv >> 2));
        const int kb8c = (kb * 4 + quad) * 64;
        s8 wlv = wlb_n;
        s8 ahb_c[4];
#pragma unroll
        for (int mt = 0; mt < 4; ++mt) ahb_c[mt] = z0 ? zf : ahb_n[mt];
        if (j2 < 3) {
          wlb_n = *(const s8*)(wlBs + (size_t)((j2 + 1) * 64 + lane) * 8);
          const int kbn = (wv & 3) + 4 * (2 * (j2 + 1) + (wv >> 2));
          const int kb8n = (kbn * 4 + quad) * 64;
#pragma unroll
          for (int mt = 0; mt < 4; ++mt)
            ahb_n[mt] = ldh16(H0H + (size_t)(kb8n + mt * 16 + r) * 8);
        }
        s8 alb[4];
#pragma unroll
        for (int mt = 0; mt < 4; ++mt) {
          s8 v = ldh16(H0L + (size_t)(kb8c + mt * 16 + r) * 8);
          alb[mt] = z0 ? zf : v;
        }
#pragma unroll
        for (int mt = 0; mt < 4; ++mt) {
          f4 a = accB[mt];
          a = __builtin_amdgcn_mfma_f32_16x16x32_bf16(ahb_c[mt], wBh[j2], a, 0, 0, 0);
          a = __builtin_amdgcn_mfma_f32_16x16x32_bf16(alb[mt], wBh[j2], a, 0, 0, 0);
          a = __builtin_amdgcn_mfma_f32_16x16x32_bf16(ahb_c[mt], wlv, a, 0, 0, 0);
          accB[mt] = a;
        }
      }
      if (wv >= 4) {
        const int c = wv - 4;
        s8 wlx = *(const s8*)(wlBs + (size_t)(4 * 64 + lane) * 8);
#pragma unroll
        for (int mt = 0; mt < 4; ++mt) {
          const float* sx =
              x + (size_t)(mt * 16 + r) * kT * kD + (size_t)tB * kD + c * 32 + quad * 8;
          float4 v0 = *(const float4*)sx;
          float4 v1 = *(const float4*)(sx + 4);
          float vv[8] = {v0.x, v0.y, v0.z, v0.w, v1.x, v1.y, v1.z, v1.w};
          s8 xh, xl;
#pragma unroll
          for (int e = 0; e < 8; ++e) {
            short hh, ll;
            split_bf16(vv[e], hh, ll);
            xh[e] = hh;
            xl[e] = ll;
          }
          f4 a = accB[mt];
          a = __builtin_amdgcn_mfma_f32_16x16x32_bf16(xh, wBx, a, 0, 0, 0);
          a = __builtin_amdgcn_mfma_f32_16x16x32_bf16(xl, wBx, a, 0, 0, 0);
          a = __builtin_amdgcn_mfma_f32_16x16x32_bf16(xh, wlx, a, 0, 0, 0);
          accB[mt] = a;
        }
      }
#pragma unroll
      for (int mt = 0; mt < 4; ++mt)
#pragma unroll
        for (int v = 0; v < 4; ++v)
          atomicAdd(&zB[(mt * 16 + quad * 4 + v) * 18 + r], accB[mt][v]);
    }

    __syncthreads();

    // ---- gates + h store (fragment-contiguous H2 layout, coherent stores) ----
    if (tA >= 0 && tA < kT) {
      const int par = tA & 1;
      u16* HH = hhi + (size_t)(lA * 2 + par) * BH;
      u16* HL = hlo + (size_t)(lA * 2 + par) * BH;
#pragma unroll
      for (int rp = 0; rp < 2; ++rp) {
        int p2 = tid + 512 * rp;
        int b = p2 >> 4, u = p2 & 15;
        float zi = zA[b * 66 + u] + bA[0];
        float zfg = zA[b * 66 + 16 + u] + bA[1];
        float zg = zA[b * 66 + 32 + u] + bA[2];
        float zo = zA[b * 66 + 48 + u] + bA[3];
        float cp = (tA == 0) ? 0.f : (rp ? cA1 : cA0);
        float cn = sigf(zfg) * cp + sigf(zi) * tanh_s(zg);
        float hn = sigf(zo) * tanh_s(cn);
        if (rp) cA1 = cn; else cA0 = cn;
        short hh, ll;
        split_bf16(hn, hh, ll);
        size_t off = ((size_t)(jb * 2 + (u >> 3)) * 64 + b) * 8 + (u & 7);
        sth(HH + off, (u16)hh);
        sth(HL + off, (u16)ll);
      }
    }
    if (tB < kT && tid < 256) {
      const int par = tB & 1;
      u16* HH = hhi + (size_t)par * BH;
      u16* HL = hlo + (size_t)par * BH;
      int b = tid >> 2, u2 = tid & 3;
      float zi = zB[b * 18 + u2] + bB[0];
      float zfg = zB[b * 18 + 4 + u2] + bB[1];
      float zg = zB[b * 18 + 8 + u2] + bB[2];
      float zo = zB[b * 18 + 12 + u2] + bB[3];
      float cp = (tB == 0) ? 0.f : cB0;
      float cn = sigf(zfg) * cp + sigf(zi) * tanh_s(zg);
      float hn = sigf(zo) * tanh_s(cn);
      cB0 = cn;
      short hh, ll;
      split_bf16(hn, hh, ll);
      int uglob = ub + u2;
      size_t off = ((size_t)(uglob >> 3) * 64 + b) * 8 + (uglob & 7);
      sth(HH + off, (u16)hh);
      sth(HL + off, (u16)ll);
    }

    // ---- lightweight grid barrier (no L2 writeback/invalidate) ----
    // h stores are sc1 write-through: vmcnt ack == visible at coherence point.
    asm volatile("s_waitcnt vmcnt(0) lgkmcnt(0)" ::: "memory");
    __syncthreads();
    if (tid == 0) {
      __hip_atomic_fetch_add(&bar[s], 1u, __ATOMIC_RELEASE, __HIP_MEMORY_SCOPE_AGENT);
      while (__hip_atomic_load(&bar[s], __ATOMIC_RELAXED, __HIP_MEMORY_SCOPE_AGENT) <
             (unsigned)NBLK)
        __builtin_amdgcn_s_sleep(1);
    }
    __syncthreads();
    asm volatile("" ::: "memory");
  }

  // ---- head ----
  if (g < 80) {
    int p = g * 8 + wv;
    int b = p / 10, cc = p - b * 10;
    const u16* HH = hhi + (size_t)(4 * 2 + 1) * BH;
    const u16* HL = hlo + (size_t)(4 * 2 + 1) * BH;
    float sum = 0.f;
    for (int j = lane; j < kH; j += 64) {
      size_t off = ((size_t)(j >> 3) * 64 + b) * 8 + (j & 7);
      sum += (bf2f(ldh(HH + off)) + bf2f(ldh(HL + off))) * W_head[(size_t)j * kC + cc];
    }
#pragma unroll
    for (int off = 32; off > 0; off >>= 1) sum += __shfl_down(sum, off, 64);
    if (lane == 0) out[p] = sum + b_head[cc];
  }
}

// Fallback weight-lo buffer (+ barrier counters tail), allocated at library load.
static u16* g_wl = nullptr;
__attribute__((constructor)) static void alloc_wl() {
  hipMalloc((void**)&g_wl, (WLA_ELEMS + WLB_ELEMS) * sizeof(u16) + 4096);
}

extern "C" void kernel_launch(void* const* d_in, const int* in_sizes, int n_in,
                              void* d_out, int out_size, void* d_ws, size_t ws_size,
                              hipStream_t stream) {
  const float* x = (const float*)d_in[0];
  const float* Wx0 = (const float*)d_in[1];
  const float* Wxs = (const float*)d_in[2];
  const float* Whs = (const float*)d_in[3];
  const float* bs = (const float*)d_in[4];
  const float* W_head = (const float*)d_in[5];
  const float* b_head = (const float*)d_in[6];
  float* out = (float*)d_out;

  u16* hhi = (u16*)d_ws;
  u16* hlo = hhi + H_ELEMS;
  u16* ws_wl = hlo + H_ELEMS;
  size_t need = (2 * H_ELEMS + WLA_ELEMS + WLB_ELEMS) * sizeof(u16) + 4096;
  u16 *wlA, *wlB;
  unsigned* bar;
  if (ws_size >= need) {
    wlA = ws_wl;
    wlB = wlA + WLA_ELEMS;
    bar = (unsigned*)(wlB + WLB_ELEMS);
  } else {
    wlA = g_wl;
    wlB = g_wl + WLA_ELEMS;
    bar = (unsigned*)(g_wl + WLA_ELEMS + WLB_ELEMS);
  }

  split_wl<<<256, 512, 0, stream>>>(Wx0, Wxs, Whs, wlA, wlB, bar);

  void* args[] = {&x, &Wx0, &Wxs, &Whs, &bs, &W_head, &b_head,
                  &out, &hhi, &hlo, &wlA, &wlB, &bar};
  hipLaunchCooperativeKernel((void*)lstm_persist, dim3(256), dim3(512), args, 0,
                             stream);
}

// Round 3
// 20579.291 us; speedup vs baseline: 1.3455x; 1.1001x over previous
//
#include <hip/hip_runtime.h>
#include <hip/hip_cooperative_groups.h>
#include <hip/hip_bf16.h>
#include <cstddef>

typedef unsigned short u16;
typedef unsigned long long u64t;
typedef __attribute__((ext_vector_type(8))) short s8;   // 8 bf16 = 4 VGPRs
typedef __attribute__((ext_vector_type(4))) float f4;   // MFMA acc

constexpr int kB = 64, kT = 256, kD = 128, kH = 1024, kL = 5, kC = 10, kG = 4096;
constexpr int BH = kB * kH;
constexpr size_t WLA_ELEMS = (size_t)256 * 8 * 16384;   // 67 MB of u16
constexpr size_t WLB_ELEMS = (size_t)256 * 8 * 2560;    // 10.5 MB
constexpr size_t H2_ELEMS = (size_t)kL * kT * BH;       // unique buffer per (l,t)
constexpr int NBLK = 256;

// h activations are stored FRAGMENT-CONTIGUOUS: H2[k>>3][b][k&7] (u16), i.e.
// flat index ((k>>3)*64 + b)*8 + (k&7).
//
// THIS REVISION: kill the 256 MB/step coherent-path h read traffic.
//   * Every (layer, timestep) gets a UNIQUE h buffer (320 MB scratch). A
//     reader's load address is therefore first-touch on its XCD: no stale
//     L1/L2 line can exist, so h reads become PLAIN CACHED 16B loads. The
//     64-block-per-layer duplication is now served by L1/L2 instead of the
//     cross-die coherent fabric (which ate ~80 us/step in R0-R2).
//   * Writers stay write-through agent-scope stores (R2-proven), but staged
//     through LDS and coalesced to 8B/lane: 524k -> 65k fabric txns/step.
//   * Barrier fetch_add is RELAXED (ordering = explicit vmcnt(0) drain of the
//     write-through stores). RELEASE at agent scope can emit L2 writeback.
//   * wl LDS-DMA ring (vmcnt(4) counted) unchanged.

__device__ __forceinline__ float sigf(float x) { return 1.f / (1.f + __expf(-x)); }
__device__ __forceinline__ float tanh_s(float x) {
  float ax = fabsf(x);
  float e = __expf(-2.f * ax);
  float r = (1.f - e) / (1.f + e);
  return copysignf(r, x);
}
__device__ __forceinline__ void split_bf16(float v, short& hi, short& lo) {
  __hip_bfloat16 h = __float2bfloat16(v);
  hi = __builtin_bit_cast(short, h);
  float fh = __bfloat162float(h);
  __hip_bfloat16 l = __float2bfloat16(v - fh);
  lo = __builtin_bit_cast(short, l);
}
__device__ __forceinline__ short hi_bf16(float v) {
  __hip_bfloat16 h = __float2bfloat16(v);
  return __builtin_bit_cast(short, h);
}
__device__ __forceinline__ float bf2f(u16 v) {
  unsigned u = ((unsigned)v) << 16;
  return __builtin_bit_cast(float, u);
}

// write-through 8B store, visible at the agent coherence point once vmcnt acks
__device__ __forceinline__ void sth8(u16* p, u64t v) {
  __hip_atomic_store((u64t*)p, v, __ATOMIC_RELAXED, __HIP_MEMORY_SCOPE_AGENT);
}

// async 16B/lane global->LDS DMA. LDS dest is wave-uniform base + lane*16;
// global src is per-lane. Tracked by vmcnt.
__device__ __forceinline__ void dma16(const void* gsrc, void* ldst) {
  __builtin_amdgcn_global_load_lds(
      (const __attribute__((address_space(1))) void*)gsrc,
      (__attribute__((address_space(3))) void*)ldst, 16, 0, 0);
}

// ---- prep: split weights, write LO parts in per-(block,wave) fragment order ----
__global__ void __launch_bounds__(512) split_wl(const float* __restrict__ Wx0,
                                                const float* __restrict__ Wxs,
                                                const float* __restrict__ Whs,
                                                u16* __restrict__ wlA,
                                                u16* __restrict__ wlB,
                                                unsigned* __restrict__ bar) {
  const int g = blockIdx.x, tid = threadIdx.x;
  const int wv = tid >> 6, lane = tid & 63, quad = lane >> 4, r = lane & 15;
  const int lA = (g >> 6) + 1, jb = g & 63, kq = wv & 3, ch = wv >> 2;
  const float* WxA = Wxs + (size_t)(lA - 1) * kH * kG;
  const float* WhA = Whs + (size_t)lA * kH * kG;

  if (g == 0 && tid < 512) bar[tid] = 0;  // re-zero barrier counters each launch

  u16* dA = wlA + (size_t)(g * 8 + wv) * 16384;
  for (int p = 0; p < 16; ++p) {
    int kc = 4 * p + kq;
    const float* W = (kc < 32) ? WxA : WhA;
    int krow0 = (kc & 31) * 32 + quad * 8;
    for (int ntl = 0; ntl < 2; ++ntl) {
      int col = (2 * ch + ntl) * kH + jb * 16 + r;
      s8 l8;
      for (int j = 0; j < 8; ++j) {
        float w = W[(size_t)(krow0 + j) * kG + col];
        short hh, ll;
        split_bf16(w, hh, ll);
        l8[j] = ll;
      }
      *(s8*)(dA + (size_t)((p * 2 + ntl) * 64 + lane) * 8) = l8;
    }
  }

  u16* dB = wlB + (size_t)(g * 8 + wv) * 2560;
  int colB = (r >> 2) * kH + g * 4 + (r & 3);
  for (int j2 = 0; j2 < 4; ++j2) {
    int kb = (wv & 3) + 4 * (2 * j2 + (wv >> 2));
    int krow0 = kb * 32 + quad * 8;
    s8 l8;
    for (int j = 0; j < 8; ++j) {
      float w = Whs[(size_t)(krow0 + j) * kG + colB];
      short hh, ll;
      split_bf16(w, hh, ll);
      l8[j] = ll;
    }
    *(s8*)(dB + (size_t)(j2 * 64 + lane) * 8) = l8;
  }
  {
    int krow0 = (wv & 3) * 32 + quad * 8;
    s8 l8;
    for (int j = 0; j < 8; ++j) {
      float w = Wx0[(size_t)(krow0 + j) * kG + colB];
      short hh, ll;
      split_bf16(w, hh, ll);
      l8[j] = ll;
    }
    *(s8*)(dB + (size_t)(4 * 64 + lane) * 8) = l8;
  }
}

// ---- main persistent kernel ----
__global__ void __launch_bounds__(512, 2) lstm_persist(
    const float* __restrict__ x, const float* __restrict__ Wx0,
    const float* __restrict__ Wxs, const float* __restrict__ Whs,
    const float* __restrict__ bs, const float* __restrict__ W_head,
    const float* __restrict__ b_head, float* __restrict__ out,
    u16* __restrict__ hhi, u16* __restrict__ hlo,
    const u16* __restrict__ wlA, const u16* __restrict__ wlB,
    unsigned* __restrict__ bar) {
  __shared__ s8 wpark[8][4][2][64];  // 64 KB: parked Wx-lo chunks p=0..3
  __shared__ s8 wring[8][4][2][64];  // 64 KB: 4-slot DMA ring, chunks 4..15
  __shared__ float zA[64 * 66];
  __shared__ float zB[64 * 18];
  __shared__ u16 hstA[2][128][8];    // 4 KB: staged h out (task A), hi/lo
  __shared__ u16 hstB[2][64][4];     // 1 KB: staged h out (task B), hi/lo

  const int tid = threadIdx.x;
  const int wv = tid >> 6, lane = tid & 63, quad = lane >> 4, r = lane & 15;
  const int ch = wv >> 2, kq = wv & 3;
  const int g = blockIdx.x;
  const int lA = (g >> 6) + 1;
  const int jb = g & 63;
  const int ub = g * 4;

  const float* __restrict__ WxA = Wxs + (size_t)(lA - 1) * kH * kG;
  const float* __restrict__ WhA = Whs + (size_t)lA * kH * kG;

  // ---- one-time: HI weight fragments into registers (AGPR-backed) ----
  s8 wA[16][2];  // 128 regs
#pragma unroll
  for (int p = 0; p < 16; ++p) {
    int kc = 4 * p + kq;
    const float* W = (kc < 32) ? WxA : WhA;
    int krow0 = (kc & 31) * 32 + quad * 8;
#pragma unroll
    for (int ntl = 0; ntl < 2; ++ntl) {
      int col = (2 * ch + ntl) * kH + jb * 16 + r;
      s8 h8;
#pragma unroll
      for (int j = 0; j < 8; ++j) h8[j] = hi_bf16(W[(size_t)(krow0 + j) * kG + col]);
      wA[p][ntl] = h8;
    }
  }
  s8 wBh[4], wBx;
  {
    int colB = (r >> 2) * kH + ub + (r & 3);
#pragma unroll
    for (int j2 = 0; j2 < 4; ++j2) {
      int kb = (wv & 3) + 4 * (2 * j2 + (wv >> 2));
      int krow0 = kb * 32 + quad * 8;
      s8 h8;
#pragma unroll
      for (int j = 0; j < 8; ++j) h8[j] = hi_bf16(Whs[(size_t)(krow0 + j) * kG + colB]);
      wBh[j2] = h8;
    }
    int krow0 = (wv & 3) * 32 + quad * 8;
    s8 h8;
#pragma unroll
    for (int j = 0; j < 8; ++j) h8[j] = hi_bf16(Wx0[(size_t)(krow0 + j) * kG + colB]);
    wBx = h8;
  }

  const u16* wlAs = wlA + (size_t)(g * 8 + wv) * 16384;
  const u16* wlBs = wlB + (size_t)(g * 8 + wv) * 2560;

  // ---- one-time: parked Wx-lo fragments (p=0..3) into LDS ----
#pragma unroll
  for (int p = 0; p < 4; ++p)
#pragma unroll
    for (int ntl = 0; ntl < 2; ++ntl)
      wpark[wv][p][ntl][lane] =
          *(const s8*)(wlAs + (size_t)((p * 2 + ntl) * 64 + lane) * 8);

  float bA[4], bB[4];
  {
    int u = tid & 15;
#pragma unroll
    for (int g4 = 0; g4 < 4; ++g4) bA[g4] = bs[(size_t)lA * kG + g4 * kH + jb * 16 + u];
    int u2 = tid & 3;
#pragma unroll
    for (int g4 = 0; g4 < 4; ++g4) bB[g4] = bs[(size_t)g4 * kH + ub + u2];
  }
  float cA0 = 0.f, cA1 = 0.f, cB0 = 0.f;
  const s8 zf = {0, 0, 0, 0, 0, 0, 0, 0};
  const f4 zero4 = {0.f, 0.f, 0.f, 0.f};
  const int fragbase = kq * 4 + quad;  // kk8 offset within a 16-group (128 k)

  __syncthreads();

  // ---- wavefront loop ----
  for (int s = 0; s < kT + kL - 1; ++s) {
    const int tA = s - lA;
    const int tB = s;

    for (int i = tid; i < 64 * 66; i += 512) zA[i] = 0.f;
    for (int i = tid; i < 64 * 18; i += 512) zB[i] = 0.f;
    __syncthreads();

    // ---- task A: 64 cols of layer lA; p=0..3 parked-LDS, 4..15 via DMA ring ----
    if (tA >= 0 && tA < kT) {
      const int tAm1 = (tA > 0) ? tA - 1 : 0;
      const u16* IH = hhi + ((size_t)(lA - 1) * kT + tA) * BH;
      const u16* IL = hlo + ((size_t)(lA - 1) * kT + tA) * BH;
      const u16* RH = hhi + ((size_t)lA * kT + tAm1) * BH;
      const u16* RL = hlo + ((size_t)lA * kT + tAm1) * BH;
      const bool zz = (tA == 0);
      f4 accA[2][4];
#pragma unroll
      for (int a = 0; a < 2; ++a)
#pragma unroll
        for (int b = 0; b < 4; ++b) accA[a][b] = zero4;

      // prologue: start ring DMAs for chunks 4,5 and prefetch h for p=0.
#pragma unroll
      for (int c = 4; c <= 5; ++c)
#pragma unroll
        for (int ntl = 0; ntl < 2; ++ntl)
          dma16(wlAs + (size_t)((c * 2 + ntl) * 64 + lane) * 8,
                &wring[wv][c & 3][ntl][0]);
      s8 ah_n[4], al_n[4];
#pragma unroll
      for (int mt = 0; mt < 4; ++mt) {
        ah_n[mt] = *(const s8*)(IH + (size_t)(fragbase * 64 + mt * 16 + r) * 8);
        al_n[mt] = *(const s8*)(IL + (size_t)(fragbase * 64 + mt * 16 + r) * 8);
      }

#pragma unroll
      for (int p = 0; p < 16; ++p) {
        const bool curR = (p >= 8);
        // pin iteration boundary: nothing moves across (keeps the vmcnt
        // counting argument valid and orders ring read-vs-refill).
        __builtin_amdgcn_sched_barrier(0);
        if (p >= 4) {
          // chunk p's 2 DMAs were issued >=3 iters ago and have >=4 younger
          // vmem ops; vmcnt retires in issue order, so <=4 outstanding =>
          // chunk p landed in LDS. h-register deps are compiler-tracked.
          asm volatile("s_waitcnt vmcnt(4)" ::: "memory");
          __builtin_amdgcn_sched_barrier(0);
        }
        // wl for current p
        s8 wl0, wl1;
        if (p < 4) {
          wl0 = wpark[wv][p][0][lane];
          wl1 = wpark[wv][p][1][lane];
        } else {
          wl0 = wring[wv][p & 3][0][lane];
          wl1 = wring[wv][p & 3][1][lane];
        }
        // current h frags (prefetched last iter), zero-masked at t==0
        s8 ah_c[4], al_c[4];
#pragma unroll
        for (int mt = 0; mt < 4; ++mt) {
          ah_c[mt] = (curR && zz) ? zf : ah_n[mt];
          al_c[mt] = (curR && zz) ? zf : al_n[mt];
        }
        // prefetch next h (hi AND lo) — plain cached loads
        if (p < 15) {
          const int pn = p + 1;
          const u16* SH = (pn >= 8) ? RH : IH;
          const u16* SL = (pn >= 8) ? RL : IL;
          const int kb8 = ((pn & 7) * 16 + fragbase) * 64;
#pragma unroll
          for (int mt = 0; mt < 4; ++mt) {
            ah_n[mt] = *(const s8*)(SH + (size_t)(kb8 + mt * 16 + r) * 8);
            al_n[mt] = *(const s8*)(SL + (size_t)(kb8 + mt * 16 + r) * 8);
          }
        }
        // ring refill, distance 3: chunk p+3 -> slot (p+3)&3 == (p-1)&3,
        // whose previous tenant (chunk p-1) was register-captured last iter.
        if (p >= 3 && p <= 12) {
          const int c = p + 3;
#pragma unroll
          for (int ntl = 0; ntl < 2; ++ntl)
            dma16(wlAs + (size_t)((c * 2 + ntl) * 64 + lane) * 8,
                  &wring[wv][c & 3][ntl][0]);
        }
#pragma unroll
        for (int mt = 0; mt < 4; ++mt) {
          f4 a0 = accA[0][mt], a1 = accA[1][mt];
          a0 = __builtin_amdgcn_mfma_f32_16x16x32_bf16(ah_c[mt], wA[p][0], a0, 0, 0, 0);
          a0 = __builtin_amdgcn_mfma_f32_16x16x32_bf16(al_c[mt], wA[p][0], a0, 0, 0, 0);
          a0 = __builtin_amdgcn_mfma_f32_16x16x32_bf16(ah_c[mt], wl0, a0, 0, 0, 0);
          a1 = __builtin_amdgcn_mfma_f32_16x16x32_bf16(ah_c[mt], wA[p][1], a1, 0, 0, 0);
          a1 = __builtin_amdgcn_mfma_f32_16x16x32_bf16(al_c[mt], wA[p][1], a1, 0, 0, 0);
          a1 = __builtin_amdgcn_mfma_f32_16x16x32_bf16(ah_c[mt], wl1, a1, 0, 0, 0);
          accA[0][mt] = a0;
          accA[1][mt] = a1;
        }
      }
#pragma unroll
      for (int ntl = 0; ntl < 2; ++ntl)
#pragma unroll
        for (int mt = 0; mt < 4; ++mt)
#pragma unroll
          for (int v = 0; v < 4; ++v)
            atomicAdd(&zA[(mt * 16 + quad * 4 + v) * 66 + (2 * ch + ntl) * 16 + r],
                      accA[ntl][mt][v]);
    }

    // ---- task B: 4 units of layer 0 ----
    if (tB < kT) {
      const int tBm1 = (tB > 0) ? tB - 1 : 0;
      const u16* H0H = hhi + (size_t)tBm1 * BH;
      const u16* H0L = hlo + (size_t)tBm1 * BH;
      const bool z0 = (tB == 0);
      f4 accB[4];
#pragma unroll
      for (int b = 0; b < 4; ++b) accB[b] = zero4;

      s8 wlb_n = *(const s8*)(wlBs + (size_t)(0 * 64 + lane) * 8);
      s8 ahb_n[4];
      {
        const int kb0 = (wv & 3) + 4 * (wv >> 2);
        const int kb8 = (kb0 * 4 + quad) * 64;
#pragma unroll
        for (int mt = 0; mt < 4; ++mt)
          ahb_n[mt] = *(const s8*)(H0H + (size_t)(kb8 + mt * 16 + r) * 8);
      }
#pragma unroll
      for (int j2 = 0; j2 < 4; ++j2) {
        const int kb = (wv & 3) + 4 * (2 * j2 + (wv >> 2));
        const int kb8c = (kb * 4 + quad) * 64;
        s8 wlv = wlb_n;
        s8 ahb_c[4];
#pragma unroll
        for (int mt = 0; mt < 4; ++mt) ahb_c[mt] = z0 ? zf : ahb_n[mt];
        if (j2 < 3) {
          wlb_n = *(const s8*)(wlBs + (size_t)((j2 + 1) * 64 + lane) * 8);
          const int kbn = (wv & 3) + 4 * (2 * (j2 + 1) + (wv >> 2));
          const int kb8n = (kbn * 4 + quad) * 64;
#pragma unroll
          for (int mt = 0; mt < 4; ++mt)
            ahb_n[mt] = *(const s8*)(H0H + (size_t)(kb8n + mt * 16 + r) * 8);
        }
        s8 alb[4];
#pragma unroll
        for (int mt = 0; mt < 4; ++mt) {
          s8 v = *(const s8*)(H0L + (size_t)(kb8c + mt * 16 + r) * 8);
          alb[mt] = z0 ? zf : v;
        }
#pragma unroll
        for (int mt = 0; mt < 4; ++mt) {
          f4 a = accB[mt];
          a = __builtin_amdgcn_mfma_f32_16x16x32_bf16(ahb_c[mt], wBh[j2], a, 0, 0, 0);
          a = __builtin_amdgcn_mfma_f32_16x16x32_bf16(alb[mt], wBh[j2], a, 0, 0, 0);
          a = __builtin_amdgcn_mfma_f32_16x16x32_bf16(ahb_c[mt], wlv, a, 0, 0, 0);
          accB[mt] = a;
        }
      }
      if (wv >= 4) {
        const int c = wv - 4;
        s8 wlx = *(const s8*)(wlBs + (size_t)(4 * 64 + lane) * 8);
#pragma unroll
        for (int mt = 0; mt < 4; ++mt) {
          const float* sx =
              x + (size_t)(mt * 16 + r) * kT * kD + (size_t)tB * kD + c * 32 + quad * 8;
          float4 v0 = *(const float4*)sx;
          float4 v1 = *(const float4*)(sx + 4);
          float vv[8] = {v0.x, v0.y, v0.z, v0.w, v1.x, v1.y, v1.z, v1.w};
          s8 xh, xl;
#pragma unroll
          for (int e = 0; e < 8; ++e) {
            short hh, ll;
            split_bf16(vv[e], hh, ll);
            xh[e] = hh;
            xl[e] = ll;
          }
          f4 a = accB[mt];
          a = __builtin_amdgcn_mfma_f32_16x16x32_bf16(xh, wBx, a, 0, 0, 0);
          a = __builtin_amdgcn_mfma_f32_16x16x32_bf16(xl, wBx, a, 0, 0, 0);
          a = __builtin_amdgcn_mfma_f32_16x16x32_bf16(xh, wlx, a, 0, 0, 0);
          accB[mt] = a;
        }
      }
#pragma unroll
      for (int mt = 0; mt < 4; ++mt)
#pragma unroll
        for (int v = 0; v < 4; ++v)
          atomicAdd(&zB[(mt * 16 + quad * 4 + v) * 18 + r], accB[mt][v]);
    }

    __syncthreads();

    // ---- gates; stage h into LDS (fragment-contiguous order) ----
    if (tA >= 0 && tA < kT) {
#pragma unroll
      for (int rp = 0; rp < 2; ++rp) {
        int p2 = tid + 512 * rp;
        int b = p2 >> 4, u = p2 & 15;
        float zi = zA[b * 66 + u] + bA[0];
        float zfg = zA[b * 66 + 16 + u] + bA[1];
        float zg = zA[b * 66 + 32 + u] + bA[2];
        float zo = zA[b * 66 + 48 + u] + bA[3];
        float cp = (tA == 0) ? 0.f : (rp ? cA1 : cA0);
        float cn = sigf(zfg) * cp + sigf(zi) * tanh_s(zg);
        float hn = sigf(zo) * tanh_s(cn);
        if (rp) cA1 = cn; else cA0 = cn;
        short hh, ll;
        split_bf16(hn, hh, ll);
        hstA[0][(u >> 3) * 64 + b][u & 7] = (u16)hh;
        hstA[1][(u >> 3) * 64 + b][u & 7] = (u16)ll;
      }
    }
    if (tB < kT && tid < 256) {
      int b = tid >> 2, u2 = tid & 3;
      float zi = zB[b * 18 + u2] + bB[0];
      float zfg = zB[b * 18 + 4 + u2] + bB[1];
      float zg = zB[b * 18 + 8 + u2] + bB[2];
      float zo = zB[b * 18 + 12 + u2] + bB[3];
      float cp = (tB == 0) ? 0.f : cB0;
      float cn = sigf(zfg) * cp + sigf(zi) * tanh_s(zg);
      float hn = sigf(zo) * tanh_s(cn);
      cB0 = cn;
      short hh, ll;
      split_bf16(hn, hh, ll);
      hstB[0][b][u2] = (u16)hh;
      hstB[1][b][u2] = (u16)ll;
    }
    __syncthreads();

    // ---- coalesced write-through h stores (8B/lane, ack at fabric) ----
    if (tA >= 0 && tA < kT) {
      u16* HA = ((wv < 4) ? hhi : hlo) + ((size_t)lA * kT + tA) * BH;
      const int arr = wv >> 2;               // 0: hi, 1: lo
      const int ci = (wv & 3) * 64 + lane;   // 0..255 8B-chunks
      const int gi = ci >> 1, half = ci & 1;
      u64t v = *(const u64t*)&hstA[arr][gi][half * 4];
      sth8(HA + ((size_t)(jb * 2 + (gi >> 6)) * 64 + (gi & 63)) * 8 + half * 4, v);
    }
    if (tB < kT && wv < 2) {
      u16* HB = (wv ? hlo : hhi) + (size_t)tB * BH;
      u64t v = *(const u64t*)&hstB[wv][lane][0];
      sth8(HB + ((size_t)(ub >> 3) * 64 + lane) * 8 + (ub & 7), v);
    }

    // ---- lightweight grid barrier (no L2 writeback/invalidate) ----
    // write-through stores ack at the coherence point; vmcnt drain orders
    // them before the (relaxed) arrive.
    asm volatile("s_waitcnt vmcnt(0) lgkmcnt(0)" ::: "memory");
    __syncthreads();
    if (tid == 0) {
      __hip_atomic_fetch_add(&bar[s], 1u, __ATOMIC_RELAXED, __HIP_MEMORY_SCOPE_AGENT);
      while (__hip_atomic_load(&bar[s], __ATOMIC_RELAXED, __HIP_MEMORY_SCOPE_AGENT) <
             (unsigned)NBLK)
        __builtin_amdgcn_s_sleep(1);
    }
    __syncthreads();
    asm volatile("" ::: "memory");
  }

  // ---- head ----
  if (g < 80) {
    int p = g * 8 + wv;
    int b = p / 10, cc = p - b * 10;
    const u16* HH = hhi + ((size_t)kL * kT - 1) * BH;
    const u16* HL = hlo + ((size_t)kL * kT - 1) * BH;
    float sum = 0.f;
    for (int j = lane; j < kH; j += 64) {
      size_t off = ((size_t)(j >> 3) * 64 + b) * 8 + (j & 7);
      sum += (bf2f(HH[off]) + bf2f(HL[off])) * W_head[(size_t)j * kC + cc];
    }
#pragma unroll
    for (int off = 32; off > 0; off >>= 1) sum += __shfl_down(sum, off, 64);
    if (lane == 0) out[p] = sum + b_head[cc];
  }
}

// Fallback buffer (wl + per-(l,t) h + barrier counters), allocated at load.
static u16* g_wl = nullptr;
__attribute__((constructor)) static void alloc_wl() {
  hipMalloc((void**)&g_wl,
            (WLA_ELEMS + WLB_ELEMS + 2 * H2_ELEMS) * sizeof(u16) + 4096);
}

extern "C" void kernel_launch(void* const* d_in, const int* in_sizes, int n_in,
                              void* d_out, int out_size, void* d_ws, size_t ws_size,
                              hipStream_t stream) {
  const float* x = (const float*)d_in[0];
  const float* Wx0 = (const float*)d_in[1];
  const float* Wxs = (const float*)d_in[2];
  const float* Whs = (const float*)d_in[3];
  const float* bs = (const float*)d_in[4];
  const float* W_head = (const float*)d_in[5];
  const float* b_head = (const float*)d_in[6];
  float* out = (float*)d_out;

  size_t need = (2 * H2_ELEMS + WLA_ELEMS + WLB_ELEMS) * sizeof(u16) + 4096;
  u16* base = (ws_size >= need) ? (u16*)d_ws : g_wl;
  u16* hhi = base;
  u16* hlo = hhi + H2_ELEMS;
  u16* wlA = hlo + H2_ELEMS;
  u16* wlB = wlA + WLA_ELEMS;
  unsigned* bar = (unsigned*)(wlB + WLB_ELEMS);

  split_wl<<<256, 512, 0, stream>>>(Wx0, Wxs, Whs, wlA, wlB, bar);

  void* args[] = {&x, &Wx0, &Wxs, &Whs, &bs, &W_head, &b_head,
                  &out, &hhi, &hlo, &wlA, &wlB, &bar};
  hipLaunchCooperativeKernel((void*)lstm_persist, dim3(256), dim3(512), args, 0,
                             stream);
}

// Round 4
// 20356.770 us; speedup vs baseline: 1.3602x; 1.0109x over previous
//
#include <hip/hip_runtime.h>
#include <hip/hip_cooperative_groups.h>
#include <hip/hip_bf16.h>
#include <cstddef>

typedef unsigned short u16;
typedef unsigned long long u64t;
typedef __attribute__((ext_vector_type(8))) short s8;   // 8 bf16 = 4 VGPRs
typedef __attribute__((ext_vector_type(4))) float f4;   // MFMA acc

constexpr int kB = 64, kT = 256, kD = 128, kH = 1024, kL = 5, kC = 10, kG = 4096;
constexpr int BH = kB * kH;
constexpr size_t WLA_ELEMS = (size_t)256 * 8 * 16384;   // 67 MB of u16
constexpr size_t WLB_ELEMS = (size_t)256 * 8 * 2560;    // 10.5 MB
constexpr size_t H2_ELEMS = (size_t)kL * kT * BH;       // unique buffer per (l,t)

// h activations are stored FRAGMENT-CONTIGUOUS: H2[k>>3][b][k&7] (u16), i.e.
// flat index ((k>>3)*64 + b)*8 + (k&7). Unique buffer per (layer, timestep)
// (R3): readers' addresses are first-touch => plain cached loads are coherent.
//
// THIS REVISION (pipeline-depth round): effective fetch rate has been pinned
// at ~1-1.3 TB/s in every round because (1) the A-loop's 1-iter h prefetch
// distance forces the compiler's auto-waitcnt to drain outstanding vmem to ~2
// EVERY iteration (pipe nearly empty ~70% of the time), and (2) the end-of-
// step single-counter spin (255 pollers, s_sleep(1), one line) is a poll
// storm that saturates a coherence slice and inflates everyone's latency.
//   * A-loop: ah prefetch distance 2 (register-neutral: al prefetch dropped;
//     al loaded at iter top, consumed LAST after the 16 ah-MFMAs); wl DMA
//     ring at distance 4 with loose counted waits vmcnt(30/28/26/20) derived
//     from exact younger-op counts (10 vmem ops/iter steady state).
//   * Barrier: 16x16 tree, monotonic counters, 128B-strided lines,
//     s_sleep backoff. <=16 pollers per line.

__device__ __forceinline__ float sigf(float x) { return 1.f / (1.f + __expf(-x)); }
__device__ __forceinline__ float tanh_s(float x) {
  float ax = fabsf(x);
  float e = __expf(-2.f * ax);
  float r = (1.f - e) / (1.f + e);
  return copysignf(r, x);
}
__device__ __forceinline__ void split_bf16(float v, short& hi, short& lo) {
  __hip_bfloat16 h = __float2bfloat16(v);
  hi = __builtin_bit_cast(short, h);
  float fh = __bfloat162float(h);
  __hip_bfloat16 l = __float2bfloat16(v - fh);
  lo = __builtin_bit_cast(short, l);
}
__device__ __forceinline__ short hi_bf16(float v) {
  __hip_bfloat16 h = __float2bfloat16(v);
  return __builtin_bit_cast(short, h);
}
__device__ __forceinline__ float bf2f(u16 v) {
  unsigned u = ((unsigned)v) << 16;
  return __builtin_bit_cast(float, u);
}

// write-through 8B store, visible at the agent coherence point once vmcnt acks
__device__ __forceinline__ void sth8(u16* p, u64t v) {
  __hip_atomic_store((u64t*)p, v, __ATOMIC_RELAXED, __HIP_MEMORY_SCOPE_AGENT);
}
__device__ __forceinline__ unsigned aload(const unsigned* p) {
  return __hip_atomic_load(p, __ATOMIC_RELAXED, __HIP_MEMORY_SCOPE_AGENT);
}

// async 16B/lane global->LDS DMA. LDS dest is wave-uniform base + lane*16;
// global src is per-lane. Tracked by vmcnt.
__device__ __forceinline__ void dma16(const void* gsrc, void* ldst) {
  __builtin_amdgcn_global_load_lds(
      (const __attribute__((address_space(1))) void*)gsrc,
      (__attribute__((address_space(3))) void*)ldst, 16, 0, 0);
}

// ---- prep: split weights, write LO parts in per-(block,wave) fragment order ----
__global__ void __launch_bounds__(512) split_wl(const float* __restrict__ Wx0,
                                                const float* __restrict__ Wxs,
                                                const float* __restrict__ Whs,
                                                u16* __restrict__ wlA,
                                                u16* __restrict__ wlB,
                                                unsigned* __restrict__ bar) {
  const int g = blockIdx.x, tid = threadIdx.x;
  const int wv = tid >> 6, lane = tid & 63, quad = lane >> 4, r = lane & 15;
  const int lA = (g >> 6) + 1, jb = g & 63, kq = wv & 3, ch = wv >> 2;
  const float* WxA = Wxs + (size_t)(lA - 1) * kH * kG;
  const float* WhA = Whs + (size_t)lA * kH * kG;

  if (g == 0)  // re-zero tree-barrier counters each launch (graph replays)
    for (int i = tid; i < 2048; i += 512) bar[i] = 0;

  u16* dA = wlA + (size_t)(g * 8 + wv) * 16384;
  for (int p = 0; p < 16; ++p) {
    int kc = 4 * p + kq;
    const float* W = (kc < 32) ? WxA : WhA;
    int krow0 = (kc & 31) * 32 + quad * 8;
    for (int ntl = 0; ntl < 2; ++ntl) {
      int col = (2 * ch + ntl) * kH + jb * 16 + r;
      s8 l8;
      for (int j = 0; j < 8; ++j) {
        float w = W[(size_t)(krow0 + j) * kG + col];
        short hh, ll;
        split_bf16(w, hh, ll);
        l8[j] = ll;
      }
      *(s8*)(dA + (size_t)((p * 2 + ntl) * 64 + lane) * 8) = l8;
    }
  }

  u16* dB = wlB + (size_t)(g * 8 + wv) * 2560;
  int colB = (r >> 2) * kH + g * 4 + (r & 3);
  for (int j2 = 0; j2 < 4; ++j2) {
    int kb = (wv & 3) + 4 * (2 * j2 + (wv >> 2));
    int krow0 = kb * 32 + quad * 8;
    s8 l8;
    for (int j = 0; j < 8; ++j) {
      float w = Whs[(size_t)(krow0 + j) * kG + colB];
      short hh, ll;
      split_bf16(w, hh, ll);
      l8[j] = ll;
    }
    *(s8*)(dB + (size_t)(j2 * 64 + lane) * 8) = l8;
  }
  {
    int krow0 = (wv & 3) * 32 + quad * 8;
    s8 l8;
    for (int j = 0; j < 8; ++j) {
      float w = Wx0[(size_t)(krow0 + j) * kG + colB];
      short hh, ll;
      split_bf16(w, hh, ll);
      l8[j] = ll;
    }
    *(s8*)(dB + (size_t)(4 * 64 + lane) * 8) = l8;
  }
}

// ---- main persistent kernel ----
__global__ void __launch_bounds__(512, 2) lstm_persist(
    const float* __restrict__ x, const float* __restrict__ Wx0,
    const float* __restrict__ Wxs, const float* __restrict__ Whs,
    const float* __restrict__ bs, const float* __restrict__ W_head,
    const float* __restrict__ b_head, float* __restrict__ out,
    u16* __restrict__ hhi, u16* __restrict__ hlo,
    const u16* __restrict__ wlA, const u16* __restrict__ wlB,
    unsigned* __restrict__ bar) {
  __shared__ s8 wpark[8][4][2][64];  // 64 KB: parked Wx-lo chunks p=0..3
  __shared__ s8 wring[8][4][2][64];  // 64 KB: 4-slot DMA ring, chunks 4..15
  __shared__ float zA[64 * 66];
  __shared__ float zB[64 * 18];
  __shared__ u16 hstA[2][128][8];    // 4 KB: staged h out (task A), hi/lo
  __shared__ u16 hstB[2][64][4];     // 1 KB: staged h out (task B), hi/lo

  const int tid = threadIdx.x;
  const int wv = tid >> 6, lane = tid & 63, quad = lane >> 4, r = lane & 15;
  const int ch = wv >> 2, kq = wv & 3;
  const int g = blockIdx.x;
  const int lA = (g >> 6) + 1;
  const int jb = g & 63;
  const int ub = g * 4;

  const float* __restrict__ WxA = Wxs + (size_t)(lA - 1) * kH * kG;
  const float* __restrict__ WhA = Whs + (size_t)lA * kH * kG;

  // ---- one-time: HI weight fragments into registers (AGPR-backed) ----
  s8 wA[16][2];  // 128 regs
#pragma unroll
  for (int p = 0; p < 16; ++p) {
    int kc = 4 * p + kq;
    const float* W = (kc < 32) ? WxA : WhA;
    int krow0 = (kc & 31) * 32 + quad * 8;
#pragma unroll
    for (int ntl = 0; ntl < 2; ++ntl) {
      int col = (2 * ch + ntl) * kH + jb * 16 + r;
      s8 h8;
#pragma unroll
      for (int j = 0; j < 8; ++j) h8[j] = hi_bf16(W[(size_t)(krow0 + j) * kG + col]);
      wA[p][ntl] = h8;
    }
  }
  s8 wBh[4], wBx;
  {
    int colB = (r >> 2) * kH + ub + (r & 3);
#pragma unroll
    for (int j2 = 0; j2 < 4; ++j2) {
      int kb = (wv & 3) + 4 * (2 * j2 + (wv >> 2));
      int krow0 = kb * 32 + quad * 8;
      s8 h8;
#pragma unroll
      for (int j = 0; j < 8; ++j) h8[j] = hi_bf16(Whs[(size_t)(krow0 + j) * kG + colB]);
      wBh[j2] = h8;
    }
    int krow0 = (wv & 3) * 32 + quad * 8;
    s8 h8;
#pragma unroll
    for (int j = 0; j < 8; ++j) h8[j] = hi_bf16(Wx0[(size_t)(krow0 + j) * kG + colB]);
    wBx = h8;
  }

  const u16* wlAs = wlA + (size_t)(g * 8 + wv) * 16384;
  const u16* wlBs = wlB + (size_t)(g * 8 + wv) * 2560;

  // ---- one-time: parked Wx-lo fragments (p=0..3) into LDS ----
#pragma unroll
  for (int p = 0; p < 4; ++p)
#pragma unroll
    for (int ntl = 0; ntl < 2; ++ntl)
      wpark[wv][p][ntl][lane] =
          *(const s8*)(wlAs + (size_t)((p * 2 + ntl) * 64 + lane) * 8);

  float bA[4], bB[4];
  {
    int u = tid & 15;
#pragma unroll
    for (int g4 = 0; g4 < 4; ++g4) bA[g4] = bs[(size_t)lA * kG + g4 * kH + jb * 16 + u];
    int u2 = tid & 3;
#pragma unroll
    for (int g4 = 0; g4 < 4; ++g4) bB[g4] = bs[(size_t)g4 * kH + ub + u2];
  }
  float cA0 = 0.f, cA1 = 0.f, cB0 = 0.f;
  const s8 zf = {0, 0, 0, 0, 0, 0, 0, 0};
  const f4 zero4 = {0.f, 0.f, 0.f, 0.f};
  const int fragbase = kq * 4 + quad;  // kk8 offset within a 16-group (128 k)

  __syncthreads();

  // ---- wavefront loop ----
  for (int s = 0; s < kT + kL - 1; ++s) {
    const int tA = s - lA;
    const int tB = s;

    for (int i = tid; i < 64 * 66; i += 512) zA[i] = 0.f;
    for (int i = tid; i < 64 * 18; i += 512) zB[i] = 0.f;
    __syncthreads();

    // ---- task A: 64 cols of layer lA; p=0..3 parked-LDS, 4..15 via DMA ring ----
    if (tA >= 0 && tA < kT) {
      const int tAm1 = (tA > 0) ? tA - 1 : 0;
      const u16* IH = hhi + ((size_t)(lA - 1) * kT + tA) * BH;
      const u16* IL = hlo + ((size_t)(lA - 1) * kT + tA) * BH;
      const u16* RH = hhi + ((size_t)lA * kT + tAm1) * BH;
      const u16* RL = hlo + ((size_t)lA * kT + tAm1) * BH;
      const bool zz = (tA == 0);
      f4 accA[2][4];
#pragma unroll
      for (int a = 0; a < 2; ++a)
#pragma unroll
        for (int b = 0; b < 4; ++b) accA[a][b] = zero4;

      // prologue: ring DMAs for chunks 4..7 (distance-4) + ah for p=0,1.
#pragma unroll
      for (int c = 4; c <= 7; ++c)
#pragma unroll
        for (int ntl = 0; ntl < 2; ++ntl)
          dma16(wlAs + (size_t)((c * 2 + ntl) * 64 + lane) * 8,
                &wring[wv][c & 3][ntl][0]);
      s8 ah_sl[2][4];  // ah prefetch ring, distance 2 (p=0,1 both input side)
#pragma unroll
      for (int pp = 0; pp < 2; ++pp)
#pragma unroll
        for (int mt = 0; mt < 4; ++mt)
          ah_sl[pp][mt] =
              *(const s8*)(IH + (size_t)((pp * 16 + fragbase) * 64 + mt * 16 + r) * 8);

#pragma unroll
      for (int p = 0; p < 16; ++p) {
        const bool curR = (p >= 8);
        __builtin_amdgcn_sched_barrier(0);
        // al for CURRENT p, issued at iter top, consumed last (after the
        // ah-MFMA cluster) — ~200cy of compute hides most of its latency.
        const u16* SL = curR ? RL : IL;
        const int kb8c = ((p & 7) * 16 + fragbase) * 64;
        s8 al_c[4];
#pragma unroll
        for (int mt = 0; mt < 4; ++mt)
          al_c[mt] = *(const s8*)(SL + (size_t)(kb8c + mt * 16 + r) * 8);
        // ring-slot guarantee, loose counted wait. Steady state: 10 vmem
        // ops/iter (4 al + 4 ah + 2 dma); chunk p's DMAs issued at end of
        // iter p-4 have 30 younger ops (28/26/20 at the tail when ah/refill
        // issues cease). vmcnt retires in order => outstanding<=N with N <=
        // younger-count implies chunk p landed.
        if (p == 15)      asm volatile("s_waitcnt vmcnt(20)" ::: "memory");
        else if (p == 14) asm volatile("s_waitcnt vmcnt(26)" ::: "memory");
        else if (p == 13) asm volatile("s_waitcnt vmcnt(28)" ::: "memory");
        else              asm volatile("s_waitcnt vmcnt(30)" ::: "memory");
        __builtin_amdgcn_sched_barrier(0);
        // wl for current p
        s8 wl0, wl1;
        if (p < 4) {
          wl0 = wpark[wv][p][0][lane];
          wl1 = wpark[wv][p][1][lane];
        } else {
          wl0 = wring[wv][p & 3][0][lane];
          wl1 = wring[wv][p & 3][1][lane];
        }
        // current ah (prefetched 2 iters ago), zero-masked at t==0
        s8 ah_c[4];
#pragma unroll
        for (int mt = 0; mt < 4; ++mt) ah_c[mt] = (curR && zz) ? zf : ah_sl[p & 1][mt];
        // ah-heavy MFMA cluster first (al still in flight)
#pragma unroll
        for (int mt = 0; mt < 4; ++mt) {
          f4 a0 = accA[0][mt], a1 = accA[1][mt];
          a0 = __builtin_amdgcn_mfma_f32_16x16x32_bf16(ah_c[mt], wA[p][0], a0, 0, 0, 0);
          a0 = __builtin_amdgcn_mfma_f32_16x16x32_bf16(ah_c[mt], wl0, a0, 0, 0, 0);
          a1 = __builtin_amdgcn_mfma_f32_16x16x32_bf16(ah_c[mt], wA[p][1], a1, 0, 0, 0);
          a1 = __builtin_amdgcn_mfma_f32_16x16x32_bf16(ah_c[mt], wl1, a1, 0, 0, 0);
          accA[0][mt] = a0;
          accA[1][mt] = a1;
        }
        // issue ah for p+2 (slot p&1 was just consumed) and ring refill p+4
        if (p < 14) {
          const int pn = p + 2;
          const u16* SH = (pn >= 8) ? RH : IH;
          const int kb8n = ((pn & 7) * 16 + fragbase) * 64;
#pragma unroll
          for (int mt = 0; mt < 4; ++mt)
            ah_sl[p & 1][mt] = *(const s8*)(SH + (size_t)(kb8n + mt * 16 + r) * 8);
        }
        if (p >= 4 && p <= 11) {
          const int c = p + 4;  // slot (p+4)&3 == p&3, freed by this iter's read
#pragma unroll
          for (int ntl = 0; ntl < 2; ++ntl)
            dma16(wlAs + (size_t)((c * 2 + ntl) * 64 + lane) * 8,
                  &wring[wv][c & 3][ntl][0]);
        }
        // al MFMA cluster (compiler inserts the al wait here)
        s8 alz[4];
#pragma unroll
        for (int mt = 0; mt < 4; ++mt) alz[mt] = (curR && zz) ? zf : al_c[mt];
#pragma unroll
        for (int mt = 0; mt < 4; ++mt) {
          accA[0][mt] =
              __builtin_amdgcn_mfma_f32_16x16x32_bf16(alz[mt], wA[p][0], accA[0][mt], 0, 0, 0);
          accA[1][mt] =
              __builtin_amdgcn_mfma_f32_16x16x32_bf16(alz[mt], wA[p][1], accA[1][mt], 0, 0, 0);
        }
      }
#pragma unroll
      for (int ntl = 0; ntl < 2; ++ntl)
#pragma unroll
        for (int mt = 0; mt < 4; ++mt)
#pragma unroll
          for (int v = 0; v < 4; ++v)
            atomicAdd(&zA[(mt * 16 + quad * 4 + v) * 66 + (2 * ch + ntl) * 16 + r],
                      accA[ntl][mt][v]);
    }

    // ---- task B: 4 units of layer 0 ----
    if (tB < kT) {
      const int tBm1 = (tB > 0) ? tB - 1 : 0;
      const u16* H0H = hhi + (size_t)tBm1 * BH;
      const u16* H0L = hlo + (size_t)tBm1 * BH;
      const bool z0 = (tB == 0);
      f4 accB[4];
#pragma unroll
      for (int b = 0; b < 4; ++b) accB[b] = zero4;

      s8 wlb_n = *(const s8*)(wlBs + (size_t)(0 * 64 + lane) * 8);
      s8 ahb_n[4];
      {
        const int kb0 = (wv & 3) + 4 * (wv >> 2);
        const int kb8 = (kb0 * 4 + quad) * 64;
#pragma unroll
        for (int mt = 0; mt < 4; ++mt)
          ahb_n[mt] = *(const s8*)(H0H + (size_t)(kb8 + mt * 16 + r) * 8);
      }
#pragma unroll
      for (int j2 = 0; j2 < 4; ++j2) {
        const int kb = (wv & 3) + 4 * (2 * j2 + (wv >> 2));
        const int kb8c = (kb * 4 + quad) * 64;
        s8 wlv = wlb_n;
        s8 ahb_c[4];
#pragma unroll
        for (int mt = 0; mt < 4; ++mt) ahb_c[mt] = z0 ? zf : ahb_n[mt];
        if (j2 < 3) {
          wlb_n = *(const s8*)(wlBs + (size_t)((j2 + 1) * 64 + lane) * 8);
          const int kbn = (wv & 3) + 4 * (2 * (j2 + 1) + (wv >> 2));
          const int kb8n = (kbn * 4 + quad) * 64;
#pragma unroll
          for (int mt = 0; mt < 4; ++mt)
            ahb_n[mt] = *(const s8*)(H0H + (size_t)(kb8n + mt * 16 + r) * 8);
        }
        s8 alb[4];
#pragma unroll
        for (int mt = 0; mt < 4; ++mt) {
          s8 v = *(const s8*)(H0L + (size_t)(kb8c + mt * 16 + r) * 8);
          alb[mt] = z0 ? zf : v;
        }
#pragma unroll
        for (int mt = 0; mt < 4; ++mt) {
          f4 a = accB[mt];
          a = __builtin_amdgcn_mfma_f32_16x16x32_bf16(ahb_c[mt], wBh[j2], a, 0, 0, 0);
          a = __builtin_amdgcn_mfma_f32_16x16x32_bf16(alb[mt], wBh[j2], a, 0, 0, 0);
          a = __builtin_amdgcn_mfma_f32_16x16x32_bf16(ahb_c[mt], wlv, a, 0, 0, 0);
          accB[mt] = a;
        }
      }
      if (wv >= 4) {
        const int c = wv - 4;
        s8 wlx = *(const s8*)(wlBs + (size_t)(4 * 64 + lane) * 8);
#pragma unroll
        for (int mt = 0; mt < 4; ++mt) {
          const float* sx =
              x + (size_t)(mt * 16 + r) * kT * kD + (size_t)tB * kD + c * 32 + quad * 8;
          float4 v0 = *(const float4*)sx;
          float4 v1 = *(const float4*)(sx + 4);
          float vv[8] = {v0.x, v0.y, v0.z, v0.w, v1.x, v1.y, v1.z, v1.w};
          s8 xh, xl;
#pragma unroll
          for (int e = 0; e < 8; ++e) {
            short hh, ll;
            split_bf16(vv[e], hh, ll);
            xh[e] = hh;
            xl[e] = ll;
          }
          f4 a = accB[mt];
          a = __builtin_amdgcn_mfma_f32_16x16x32_bf16(xh, wBx, a, 0, 0, 0);
          a = __builtin_amdgcn_mfma_f32_16x16x32_bf16(xl, wBx, a, 0, 0, 0);
          a = __builtin_amdgcn_mfma_f32_16x16x32_bf16(xh, wlx, a, 0, 0, 0);
          accB[mt] = a;
        }
      }
#pragma unroll
      for (int mt = 0; mt < 4; ++mt)
#pragma unroll
        for (int v = 0; v < 4; ++v)
          atomicAdd(&zB[(mt * 16 + quad * 4 + v) * 18 + r], accB[mt][v]);
    }

    __syncthreads();

    // ---- gates; stage h into LDS (fragment-contiguous order) ----
    if (tA >= 0 && tA < kT) {
#pragma unroll
      for (int rp = 0; rp < 2; ++rp) {
        int p2 = tid + 512 * rp;
        int b = p2 >> 4, u = p2 & 15;
        float zi = zA[b * 66 + u] + bA[0];
        float zfg = zA[b * 66 + 16 + u] + bA[1];
        float zg = zA[b * 66 + 32 + u] + bA[2];
        float zo = zA[b * 66 + 48 + u] + bA[3];
        float cp = (tA == 0) ? 0.f : (rp ? cA1 : cA0);
        float cn = sigf(zfg) * cp + sigf(zi) * tanh_s(zg);
        float hn = sigf(zo) * tanh_s(cn);
        if (rp) cA1 = cn; else cA0 = cn;
        short hh, ll;
        split_bf16(hn, hh, ll);
        hstA[0][(u >> 3) * 64 + b][u & 7] = (u16)hh;
        hstA[1][(u >> 3) * 64 + b][u & 7] = (u16)ll;
      }
    }
    if (tB < kT && tid < 256) {
      int b = tid >> 2, u2 = tid & 3;
      float zi = zB[b * 18 + u2] + bB[0];
      float zfg = zB[b * 18 + 4 + u2] + bB[1];
      float zg = zB[b * 18 + 8 + u2] + bB[2];
      float zo = zB[b * 18 + 12 + u2] + bB[3];
      float cp = (tB == 0) ? 0.f : cB0;
      float cn = sigf(zfg) * cp + sigf(zi) * tanh_s(zg);
      float hn = sigf(zo) * tanh_s(cn);
      cB0 = cn;
      short hh, ll;
      split_bf16(hn, hh, ll);
      hstB[0][b][u2] = (u16)hh;
      hstB[1][b][u2] = (u16)ll;
    }
    __syncthreads();

    // ---- coalesced write-through h stores (8B/lane, ack at fabric) ----
    if (tA >= 0 && tA < kT) {
      u16* HA = ((wv < 4) ? hhi : hlo) + ((size_t)lA * kT + tA) * BH;
      const int arr = wv >> 2;               // 0: hi, 1: lo
      const int ci = (wv & 3) * 64 + lane;   // 0..255 8B-chunks
      const int gi = ci >> 1, half = ci & 1;
      u64t v = *(const u64t*)&hstA[arr][gi][half * 4];
      sth8(HA + ((size_t)(jb * 2 + (gi >> 6)) * 64 + (gi & 63)) * 8 + half * 4, v);
    }
    if (tB < kT && wv < 2) {
      u16* HB = (wv ? hlo : hhi) + (size_t)tB * BH;
      u64t v = *(const u64t*)&hstB[wv][lane][0];
      sth8(HB + ((size_t)(ub >> 3) * 64 + lane) * 8 + (ub & 7), v);
    }

    // ---- tree grid barrier: 16 leaves x 16 blocks, monotonic counters ----
    // write-through stores ack at the coherence point; each thread drained
    // its own vmcnt before __syncthreads => block's h visible before arrive.
    asm volatile("s_waitcnt vmcnt(0) lgkmcnt(0)" ::: "memory");
    __syncthreads();
    if (tid == 0) {
      const int leaf = g >> 4;
      const unsigned tgt = 16u * (unsigned)(s + 1);
      __hip_atomic_fetch_add(&bar[leaf * 32], 1u, __ATOMIC_RELAXED,
                             __HIP_MEMORY_SCOPE_AGENT);
      if ((g & 15) == 0) {  // leaf representative
        while (aload(&bar[leaf * 32]) < tgt) __builtin_amdgcn_s_sleep(1);
        __hip_atomic_fetch_add(&bar[512], 1u, __ATOMIC_RELAXED,
                               __HIP_MEMORY_SCOPE_AGENT);
        while (aload(&bar[512]) < tgt) __builtin_amdgcn_s_sleep(2);
        __hip_atomic_store(&bar[544 + leaf * 32], (unsigned)(s + 1),
                           __ATOMIC_RELAXED, __HIP_MEMORY_SCOPE_AGENT);
      } else {
        while (aload(&bar[544 + leaf * 32]) < (unsigned)(s + 1))
          __builtin_amdgcn_s_sleep(4);
      }
    }
    __syncthreads();
    asm volatile("" ::: "memory");
  }

  // ---- head ----
  if (g < 80) {
    int p = g * 8 + wv;
    int b = p / 10, cc = p - b * 10;
    const u16* HH = hhi + ((size_t)kL * kT - 1) * BH;
    const u16* HL = hlo + ((size_t)kL * kT - 1) * BH;
    float sum = 0.f;
    for (int j = lane; j < kH; j += 64) {
      size_t off = ((size_t)(j >> 3) * 64 + b) * 8 + (j & 7);
      sum += (bf2f(HH[off]) + bf2f(HL[off])) * W_head[(size_t)j * kC + cc];
    }
#pragma unroll
    for (int off = 32; off > 0; off >>= 1) sum += __shfl_down(sum, off, 64);
    if (lane == 0) out[p] = sum + b_head[cc];
  }
}

// Fallback buffer (wl + per-(l,t) h + barrier counters), allocated at load.
static u16* g_wl = nullptr;
__attribute__((constructor)) static void alloc_wl() {
  hipMalloc((void**)&g_wl,
            (WLA_ELEMS + WLB_ELEMS + 2 * H2_ELEMS) * sizeof(u16) + 16384);
}

extern "C" void kernel_launch(void* const* d_in, const int* in_sizes, int n_in,
                              void* d_out, int out_size, void* d_ws, size_t ws_size,
                              hipStream_t stream) {
  const float* x = (const float*)d_in[0];
  const float* Wx0 = (const float*)d_in[1];
  const float* Wxs = (const float*)d_in[2];
  const float* Whs = (const float*)d_in[3];
  const float* bs = (const float*)d_in[4];
  const float* W_head = (const float*)d_in[5];
  const float* b_head = (const float*)d_in[6];
  float* out = (float*)d_out;

  size_t need = (2 * H2_ELEMS + WLA_ELEMS + WLB_ELEMS) * sizeof(u16) + 16384;
  u16* base = (ws_size >= need) ? (u16*)d_ws : g_wl;
  u16* hhi = base;
  u16* hlo = hhi + H2_ELEMS;
  u16* wlA = hlo + H2_ELEMS;
  u16* wlB = wlA + WLA_ELEMS;
  unsigned* bar = (unsigned*)(wlB + WLB_ELEMS);

  split_wl<<<256, 512, 0, stream>>>(Wx0, Wxs, Whs, wlA, wlB, bar);

  void* args[] = {&x, &Wx0, &Wxs, &Whs, &bs, &W_head, &b_head,
                  &out, &hhi, &hlo, &wlA, &wlB, &bar};
  hipLaunchCooperativeKernel((void*)lstm_persist, dim3(256), dim3(512), args, 0,
                             stream);
}